// Round 2
// baseline (61965.564 us; speedup 1.0000x reference)
//
#include <hip/hip_runtime.h>
#include <hip/hip_bf16.h>
#include <math.h>

typedef __hip_bfloat16 bf16;

#define T_SEQ 256
#define BATCH 64
#define FEATD 188
#define HID   512
#define EMB   1024
#define NTAG  14
#define G3    1536   // 3*HID

// ---------------------------------------------------------------------------
// GEMM: C[M,N] = concat(A1,A2)[M,K] @ W[N,K]^T + bias.
// A is bf16 (two segments, A2 may be null, K1 = cols of A1), W/bias fp32,
// C bf16. 64x64 tile, 256 threads, 4x4 microtile. M,N multiples of 64.
// ---------------------------------------------------------------------------
__global__ __launch_bounds__(256) void gemm_tn(
    const bf16* __restrict__ A1, int lda1,
    const bf16* __restrict__ A2, int lda2, int K1,
    const float* __restrict__ W, int ldw,
    const float* __restrict__ bias,
    bf16* __restrict__ C, int ldc,
    int M, int N, int K)
{
  __shared__ float As[16][64];
  __shared__ float Ws[16][64];
  const int bm = blockIdx.y * 64;
  const int bn = blockIdx.x * 64;
  const int tid = threadIdx.x;
  const int tx = tid & 15, ty = tid >> 4;
  float acc[4][4] = {};
  for (int k0 = 0; k0 < K; k0 += 16) {
    for (int i = tid; i < 1024; i += 256) {
      int m = i >> 4, k = i & 15;
      int kg = k0 + k;
      float av = 0.f, wv = 0.f;
      if (kg < K) {
        av = (kg < K1) ? __bfloat162float(A1[(size_t)(bm + m) * lda1 + kg])
                       : __bfloat162float(A2[(size_t)(bm + m) * lda2 + (kg - K1)]);
        wv = W[(size_t)(bn + m) * ldw + kg];
      }
      As[k][m] = av;
      Ws[k][m] = wv;
    }
    __syncthreads();
#pragma unroll
    for (int kk = 0; kk < 16; ++kk) {
      float4 av = *(const float4*)&As[kk][ty * 4];
      float4 wv = *(const float4*)&Ws[kk][tx * 4];
      float aa[4] = {av.x, av.y, av.z, av.w};
      float ww[4] = {wv.x, wv.y, wv.z, wv.w};
#pragma unroll
      for (int i = 0; i < 4; ++i)
#pragma unroll
        for (int j = 0; j < 4; ++j)
          acc[i][j] = fmaf(aa[i], ww[j], acc[i][j]);
    }
    __syncthreads();
  }
#pragma unroll
  for (int i = 0; i < 4; ++i) {
    int m = bm + ty * 4 + i;
#pragma unroll
    for (int j = 0; j < 4; ++j) {
      int n = bn + tx * 4 + j;
      float v = acc[i][j];
      if (bias) v += bias[n];
      C[(size_t)m * ldc + n] = __float2bfloat16(v);
    }
  }
}

// ---------------------------------------------------------------------------
// features [B,T,FEAT] fp32 -> xT [T,B,FEAT] bf16
// ---------------------------------------------------------------------------
__global__ __launch_bounds__(256) void transpose_feat(
    const float* __restrict__ f, bf16* __restrict__ xT)
{
  const int idx = blockIdx.x * 256 + threadIdx.x;
  const int total = BATCH * T_SEQ * FEATD;
  if (idx >= total) return;
  const int i = idx % FEATD;
  const int r = idx / FEATD;
  const int b = r / T_SEQ;
  const int t = r % T_SEQ;
  xT[((size_t)t * BATCH + b) * FEATD + i] = __float2bfloat16(f[idx]);
}

// ---------------------------------------------------------------------------
// One bidirectional GRU time step (both directions).
// xp_*: [T,B,3H] bf16 precomputed x@w_ih^T + b_ih (natural time order).
// out:  [T,B,E] bf16; fwd writes cols [0,512), bwd cols [512,1024).
// Hidden state for step s-1 read from out (written by previous launch).
// grid = 16 blocks: dir(2) x coltile(8 of 64), 256 threads.
// ---------------------------------------------------------------------------
__global__ __launch_bounds__(256) void gru_step(
    const bf16* __restrict__ xp_f, const bf16* __restrict__ xp_b,
    const float* __restrict__ whh_f, const float* __restrict__ whh_b,
    const float* __restrict__ bhh_f, const float* __restrict__ bhh_b,
    bf16* __restrict__ out, int s)
{
  const int dir = blockIdx.x >> 3;
  const int ct  = blockIdx.x & 7;
  const int t   = dir ? (T_SEQ - 1 - s) : s;
  const bf16* xp   = dir ? xp_b  : xp_f;
  const float* whh = dir ? whh_b : whh_f;
  const float* bhh = dir ? bhh_b : bhh_f;
  const int off = dir ? HID : 0;
  const bf16* hprev = nullptr;
  if (s > 0) {
    const int tp = dir ? (t + 1) : (t - 1);
    hprev = out + (size_t)tp * BATCH * EMB + off;
  }
  __shared__ float Hs[16][64];
  __shared__ float Ws[3][16][64];
  const int tid = threadIdx.x;
  const int tx = tid & 15, ty = tid >> 4;
  float acc[3][4][4] = {};
  if (s > 0) {
    for (int k0 = 0; k0 < HID; k0 += 16) {
      for (int i = tid; i < 1024; i += 256) {
        int b = i >> 4, k = i & 15;
        Hs[k][b] = __bfloat162float(hprev[(size_t)b * EMB + k0 + k]);
      }
#pragma unroll
      for (int g = 0; g < 3; ++g)
        for (int i = tid; i < 1024; i += 256) {
          int n = i >> 4, k = i & 15;
          Ws[g][k][n] = whh[(size_t)(g * HID + ct * 64 + n) * HID + k0 + k];
        }
      __syncthreads();
#pragma unroll
      for (int kk = 0; kk < 16; ++kk) {
        float4 av = *(const float4*)&Hs[kk][ty * 4];
        float4 w0 = *(const float4*)&Ws[0][kk][tx * 4];
        float4 w1 = *(const float4*)&Ws[1][kk][tx * 4];
        float4 w2 = *(const float4*)&Ws[2][kk][tx * 4];
        float aa[4]  = {av.x, av.y, av.z, av.w};
        float ww0[4] = {w0.x, w0.y, w0.z, w0.w};
        float ww1[4] = {w1.x, w1.y, w1.z, w1.w};
        float ww2[4] = {w2.x, w2.y, w2.z, w2.w};
#pragma unroll
        for (int i = 0; i < 4; ++i)
#pragma unroll
          for (int j = 0; j < 4; ++j) {
            acc[0][i][j] = fmaf(aa[i], ww0[j], acc[0][i][j]);
            acc[1][i][j] = fmaf(aa[i], ww1[j], acc[1][i][j]);
            acc[2][i][j] = fmaf(aa[i], ww2[j], acc[2][i][j]);
          }
      }
      __syncthreads();
    }
  }
  const size_t xbase = (size_t)t * BATCH * G3;
  const size_t obase = (size_t)t * BATCH * EMB + off;
#pragma unroll
  for (int i = 0; i < 4; ++i) {
    const int b = ty * 4 + i;
    const size_t xrow = xbase + (size_t)b * G3;
#pragma unroll
    for (int j = 0; j < 4; ++j) {
      const int col = ct * 64 + tx * 4 + j;
      float xr = __bfloat162float(xp[xrow + col]);
      float xz = __bfloat162float(xp[xrow + HID + col]);
      float xn = __bfloat162float(xp[xrow + 2 * HID + col]);
      float hr = acc[0][i][j] + bhh[col];
      float hz = acc[1][i][j] + bhh[HID + col];
      float hn = acc[2][i][j] + bhh[2 * HID + col];
      float hp = (s > 0) ? __bfloat162float(hprev[(size_t)b * EMB + col]) : 0.f;
      float r = 1.f / (1.f + expf(-(xr + hr)));
      float z = 1.f / (1.f + expf(-(xz + hz)));
      float n = tanhf(xn + r * hn);
      out[obase + (size_t)b * EMB + col] = __float2bfloat16((1.f - z) * n + z * hp);
    }
  }
}

// ---------------------------------------------------------------------------
// K/V projections: ne is batch-broadcast -> K/V collapse to [NT, EMB] fp32.
// ---------------------------------------------------------------------------
__global__ __launch_bounds__(256) void kv_kernel(
    const float* __restrict__ ne, const float* __restrict__ k_w,
    const float* __restrict__ k_b, const float* __restrict__ v_w,
    const float* __restrict__ v_b, float* __restrict__ kk,
    float* __restrict__ vv)
{
  const int e = blockIdx.x * 256 + threadIdx.x;
  if (e >= EMB) return;
#pragma unroll
  for (int s = 0; s < NTAG; ++s) {
    float a = k_b[e], c = v_b[e];
#pragma unroll
    for (int i = 0; i < NTAG; ++i) {
      float nv = ne[s * NTAG + i];
      a = fmaf(nv, k_w[e * NTAG + i], a);
      c = fmaf(nv, v_w[e * NTAG + i], c);
    }
    kk[s * EMB + e] = a;
    vv[s * EMB + e] = c;
  }
}

// ---------------------------------------------------------------------------
// Attention: one wave per (t*B+b, head). S=14 keys, HD=128 (2 regs/lane).
// q bf16, kk/vv fp32, ao bf16.
// ---------------------------------------------------------------------------
__global__ __launch_bounds__(64) void attn_kernel(
    const bf16* __restrict__ q, const float* __restrict__ kk,
    const float* __restrict__ vv, bf16* __restrict__ ao)
{
  const int blk = blockIdx.x;
  const int h = blk & 7;
  const int tb = blk >> 3;
  const int lane = threadIdx.x;
  const size_t qbase = (size_t)tb * EMB + h * 128;
  const int kbase = h * 128 + lane;
  float q0 = __bfloat162float(q[qbase + lane]);
  float q1 = __bfloat162float(q[qbase + 64 + lane]);
  float sc[NTAG];
#pragma unroll
  for (int j = 0; j < NTAG; ++j) {
    float p = q0 * kk[j * EMB + kbase] + q1 * kk[j * EMB + 64 + kbase];
#pragma unroll
    for (int d = 32; d; d >>= 1) p += __shfl_xor(p, d);
    sc[j] = p * 0.088388347648318447f;  // 1/sqrt(128)
  }
  float m = sc[0];
#pragma unroll
  for (int j = 1; j < NTAG; ++j) m = fmaxf(m, sc[j]);
  float sum = 0.f;
#pragma unroll
  for (int j = 0; j < NTAG; ++j) { sc[j] = expf(sc[j] - m); sum += sc[j]; }
  float inv = 1.f / sum;
  float o0 = 0.f, o1 = 0.f;
#pragma unroll
  for (int j = 0; j < NTAG; ++j) {
    float p = sc[j] * inv;
    o0 = fmaf(p, vv[j * EMB + kbase], o0);
    o1 = fmaf(p, vv[j * EMB + 64 + kbase], o1);
  }
  ao[qbase + lane] = __float2bfloat16(o0);
  ao[qbase + 64 + lane] = __float2bfloat16(o1);
}

// ---------------------------------------------------------------------------
// Fused final linear + ne-table logits: one wave per (t,b).
// dec [T,B,EMB] bf16 -> logits [B,T,NT] fp32
// ---------------------------------------------------------------------------
__global__ __launch_bounds__(64) void dec_logits_kernel(
    const bf16* __restrict__ dec, const float* __restrict__ lin_w,
    const float* __restrict__ lin_b, const float* __restrict__ ne,
    float* __restrict__ logits)
{
  const int tb = blockIdx.x;
  const int t = tb >> 6;   // /BATCH
  const int b = tb & 63;
  const int lane = threadIdx.x;
  const bf16* drow = dec + (size_t)tb * EMB;
  float dv[16];
#pragma unroll
  for (int i = 0; i < 16; ++i) dv[i] = __bfloat162float(drow[lane + 64 * i]);
  float dl[NTAG];
#pragma unroll
  for (int n = 0; n < NTAG; ++n) {
    float p = 0.f;
#pragma unroll
    for (int i = 0; i < 16; ++i)
      p = fmaf(dv[i], lin_w[n * EMB + lane + 64 * i], p);
#pragma unroll
    for (int d = 32; d; d >>= 1) p += __shfl_xor(p, d);
    dl[n] = p + lin_b[n];
  }
  if (lane < NTAG) {
    float acc = 0.f;
#pragma unroll
    for (int d2 = 0; d2 < NTAG; ++d2)
      acc = fmaf(dl[d2], ne[lane * NTAG + d2], acc);
    logits[((size_t)b * T_SEQ + t) * NTAG + lane] = acc * 0.26726124191242439f; // 1/sqrt(14)
  }
}

// ---------------------------------------------------------------------------
// CRF NLL per batch element (one wave per b; alpha recurrence over T).
// ---------------------------------------------------------------------------
__global__ __launch_bounds__(64) void crf_kernel(
    const float* __restrict__ logits, const int* __restrict__ labels,
    const float* __restrict__ cstart, const float* __restrict__ cend,
    const float* __restrict__ ctrans, float* __restrict__ lossb)
{
  const int b = blockIdx.x;
  const int lane = threadIdx.x;
  __shared__ float al[NTAG];
  __shared__ float tr[NTAG * NTAG];
  __shared__ float tmp[NTAG];
  const float* lg = logits + (size_t)b * T_SEQ * NTAG;
  const int* lab = labels + (size_t)b * T_SEQ;
  for (int i = lane; i < NTAG * NTAG; i += 64) tr[i] = ctrans[i];
  if (lane < NTAG) al[lane] = cstart[lane] + lg[lane];
  __syncthreads();
  for (int t = 1; t < T_SEQ; ++t) {
    float v = 0.f;
    if (lane < NTAG) {
      float mx = -1e30f;
#pragma unroll
      for (int i = 0; i < NTAG; ++i) mx = fmaxf(mx, al[i] + tr[i * NTAG + lane]);
      float sm = 0.f;
#pragma unroll
      for (int i = 0; i < NTAG; ++i) sm += expf(al[i] + tr[i * NTAG + lane] - mx);
      v = mx + logf(sm) + lg[t * NTAG + lane];
    }
    __syncthreads();
    if (lane < NTAG) al[lane] = v;
    __syncthreads();
  }
  float em = 0.f;
  for (int t = lane; t < T_SEQ; t += 64) em += lg[t * NTAG + lab[t]];
  float trs = 0.f;
  for (int t = lane; t < T_SEQ - 1; t += 64) trs += tr[lab[t] * NTAG + lab[t + 1]];
  float p = em + trs;
#pragma unroll
  for (int d = 32; d; d >>= 1) p += __shfl_xor(p, d);
  if (lane < NTAG) tmp[lane] = al[lane] + cend[lane];
  __syncthreads();
  if (lane == 0) {
    float num = p + cstart[lab[0]] + cend[lab[T_SEQ - 1]];
    float mx = tmp[0];
#pragma unroll
    for (int i = 1; i < NTAG; ++i) mx = fmaxf(mx, tmp[i]);
    float sm = 0.f;
#pragma unroll
    for (int i = 0; i < NTAG; ++i) sm += expf(tmp[i] - mx);
    float den = mx + logf(sm);
    lossb[b] = -(num - den);
  }
}

__global__ __launch_bounds__(64) void final_reduce(
    const float* __restrict__ lossb, float* __restrict__ out)
{
  float v = lossb[threadIdx.x];
#pragma unroll
  for (int d = 32; d; d >>= 1) v += __shfl_xor(v, d);
  if (threadIdx.x == 0) out[0] = v * (1.f / 64.f);
}

// ---------------------------------------------------------------------------
extern "C" void kernel_launch(void* const* d_in, const int* in_sizes, int n_in,
                              void* d_out, int out_size, void* d_ws, size_t ws_size,
                              hipStream_t stream)
{
  const float* features = (const float*)d_in[0];
  const int*   labels   = (const int*)d_in[1];
  const float* ne_table = (const float*)d_in[2];
  const float* g1_wih_f = (const float*)d_in[3];
  const float* g1_whh_f = (const float*)d_in[4];
  const float* g1_bih_f = (const float*)d_in[5];
  const float* g1_bhh_f = (const float*)d_in[6];
  const float* g1_wih_b = (const float*)d_in[7];
  const float* g1_whh_b = (const float*)d_in[8];
  const float* g1_bih_b = (const float*)d_in[9];
  const float* g1_bhh_b = (const float*)d_in[10];
  const float* g2_wih_f = (const float*)d_in[11];
  const float* g2_whh_f = (const float*)d_in[12];
  const float* g2_bih_f = (const float*)d_in[13];
  const float* g2_bhh_f = (const float*)d_in[14];
  const float* g2_wih_b = (const float*)d_in[15];
  const float* g2_whh_b = (const float*)d_in[16];
  const float* g2_bih_b = (const float*)d_in[17];
  const float* g2_bhh_b = (const float*)d_in[18];
  const float* q_w   = (const float*)d_in[19];
  const float* q_b   = (const float*)d_in[20];
  const float* k_w   = (const float*)d_in[21];
  const float* k_b   = (const float*)d_in[22];
  const float* v_w   = (const float*)d_in[23];
  const float* v_b   = (const float*)d_in[24];
  const float* out_w = (const float*)d_in[25];
  const float* out_b = (const float*)d_in[26];
  const float* lin_w = (const float*)d_in[27];
  const float* lin_b = (const float*)d_in[28];
  const float* crf_start = (const float*)d_in[29];
  const float* crf_end   = (const float*)d_in[30];
  const float* crf_trans = (const float*)d_in[31];

  // ---- workspace layout (aliased regions, ~193 MB total) ----
  const size_t NTB = (size_t)T_SEQ * BATCH;      // 16384
  char* base = (char*)d_ws;
  size_t off = 0;
  auto alloc = [&](size_t bytes) {
    char* p = base + off;
    off += (bytes + 255) & ~(size_t)255;
    return p;
  };
  bf16* xpA  = (bf16*)alloc(NTB * G3 * sizeof(bf16));   // xp fwd (gru1, then gru2)
  bf16* xpB  = (bf16*)alloc(NTB * G3 * sizeof(bf16));   // xp bwd
  bf16* enc  = (bf16*)alloc(NTB * EMB * sizeof(bf16));  // gru1 output
  bf16* bufD = (bf16*)alloc(NTB * EMB * sizeof(bf16));  // xT -> aoraw -> dec
  bf16* bufE = (bf16*)alloc(NTB * EMB * sizeof(bf16));  // q -> aofin
  float* kkbuf  = (float*)alloc((size_t)NTAG * EMB * sizeof(float));
  float* vvbuf  = (float*)alloc((size_t)NTAG * EMB * sizeof(float));
  float* logits = (float*)alloc(NTB * NTAG * sizeof(float));
  float* lossb  = (float*)alloc(64 * sizeof(float));
  (void)off; (void)ws_size; (void)in_sizes; (void)n_in; (void)out_size;

  bf16* xT = bufD;  // [T,B,FEAT] bf16, aliases bufD (dead before aoraw)

  const int M = (int)NTB;  // 16384
  dim3 blk(256);
  dim3 g_xp(G3 / 64, M / 64);   // (24,256)
  dim3 g_e(EMB / 64, M / 64);   // (16,256)

  // 1. features -> [T,B,FEAT] bf16
  transpose_feat<<<(BATCH * T_SEQ * FEATD + 255) / 256, blk, 0, stream>>>(features, xT);

  // 2. GRU1 input projections
  gemm_tn<<<g_xp, blk, 0, stream>>>(xT, FEATD, nullptr, 0, FEATD,
                                    g1_wih_f, FEATD, g1_bih_f, xpA, G3, M, G3, FEATD);
  gemm_tn<<<g_xp, blk, 0, stream>>>(xT, FEATD, nullptr, 0, FEATD,
                                    g1_wih_b, FEATD, g1_bih_b, xpB, G3, M, G3, FEATD);

  // 3. GRU1 recurrence -> enc
  for (int s = 0; s < T_SEQ; ++s)
    gru_step<<<16, blk, 0, stream>>>(xpA, xpB, g1_whh_f, g1_whh_b, g1_bhh_f, g1_bhh_b, enc, s);

  // 4. K/V (batch-independent) + Q projection -> bufE
  kv_kernel<<<4, blk, 0, stream>>>(ne_table, k_w, k_b, v_w, v_b, kkbuf, vvbuf);
  gemm_tn<<<g_e, blk, 0, stream>>>(enc, EMB, nullptr, 0, EMB,
                                   q_w, EMB, q_b, bufE, EMB, M, EMB, EMB);

  // 5. Attention (q=bufE -> aoraw=bufD) + output projection (-> aofin=bufE)
  attn_kernel<<<M * 8, 64, 0, stream>>>(bufE, kkbuf, vvbuf, bufD);
  gemm_tn<<<g_e, blk, 0, stream>>>(bufD, EMB, nullptr, 0, EMB,
                                   out_w, EMB, out_b, bufE, EMB, M, EMB, EMB);

  // 6. GRU2 input projections: dec_in = [enc, ao] via concat-A GEMM
  gemm_tn<<<g_xp, blk, 0, stream>>>(enc, EMB, bufE, EMB, EMB,
                                    g2_wih_f, 2 * EMB, g2_bih_f, xpA, G3, M, G3, 2 * EMB);
  gemm_tn<<<g_xp, blk, 0, stream>>>(enc, EMB, bufE, EMB, EMB,
                                    g2_wih_b, 2 * EMB, g2_bih_b, xpB, G3, M, G3, 2 * EMB);

  // 7. GRU2 recurrence -> dec (bufD; aoraw dead)
  for (int s = 0; s < T_SEQ; ++s)
    gru_step<<<16, blk, 0, stream>>>(xpA, xpB, g2_whh_f, g2_whh_b, g2_bhh_f, g2_bhh_b, bufD, s);

  // 8. Final linear + ne logits
  dec_logits_kernel<<<M, 64, 0, stream>>>(bufD, lin_w, lin_b, ne_table, logits);

  // 9. CRF NLL + mean
  crf_kernel<<<BATCH, 64, 0, stream>>>(logits, labels, crf_start, crf_end, crf_trans, lossb);
  final_reduce<<<1, 64, 0, stream>>>(lossb, (float*)d_out);
}

// Round 3
// 11577.615 us; speedup vs baseline: 5.3522x; 5.3522x over previous
//
#include <hip/hip_runtime.h>
#include <hip/hip_bf16.h>
#include <math.h>

typedef __hip_bfloat16 bf16;
typedef __bf16 bf16x8 __attribute__((ext_vector_type(8)));
typedef float  f32x4  __attribute__((ext_vector_type(4)));

#define T_SEQ 256
#define BATCH 64
#define FEATD 188
#define HID   512
#define EMB   1024
#define NTAG  14
#define G3    1536   // 3*HID

// ---------------------------------------------------------------------------
// fp32 -> bf16 weight conversion (vectorized x4; all n % 4 == 0)
// ---------------------------------------------------------------------------
__global__ __launch_bounds__(256) void f32_to_bf16(
    const float* __restrict__ src, bf16* __restrict__ dst, int n4)
{
  int i = blockIdx.x * 256 + threadIdx.x;
  if (i >= n4) return;
  float4 v = *(const float4*)(src + (size_t)i * 4);
  bf16 o[4] = {__float2bfloat16(v.x), __float2bfloat16(v.y),
               __float2bfloat16(v.z), __float2bfloat16(v.w)};
  *(ushort4*)(dst + (size_t)i * 4) = *(ushort4*)o;
}

// ---------------------------------------------------------------------------
// MFMA GEMM: C[M,N] = concat(A1,A2)[M,K] @ W[N,K]^T + bias.
// A1/A2/W bf16, bias fp32, C bf16. 128x128 tile, 256 threads (4 waves 2x2),
// 64x64 per wave = 4x4 frags of 16x16, K-step 32. M,N %128==0, K %4==0,
// K1 %4==0 (segment boundary never splits a quad).
// ---------------------------------------------------------------------------
__global__ __launch_bounds__(256) void gemm_mfma(
    const bf16* __restrict__ A1, int lda1,
    const bf16* __restrict__ A2, int lda2, int K1,
    const bf16* __restrict__ W, int ldw,
    const float* __restrict__ bias,
    bf16* __restrict__ C, int ldc,
    int M, int N, int K)
{
  __shared__ __bf16 As[128][40];   // stride 40 (80 B): 16B-aligned, <=2-way conflict
  __shared__ __bf16 Bs[128][40];
  const int bm = blockIdx.y * 128;
  const int bn = blockIdx.x * 128;
  const int tid = threadIdx.x;
  const int wave = tid >> 6, lane = tid & 63;
  const int wr = wave >> 1, wc = wave & 1;
  const int lr = lane & 15, lk = (lane >> 4) << 3;
  f32x4 acc[4][4] = {};
  for (int k0 = 0; k0 < K; k0 += 32) {
#pragma unroll
    for (int p = 0; p < 4; ++p) {
      int i = tid + p * 256;            // 0..1023
      int row = i >> 3, q = i & 7;
      int kg = k0 + q * 4;
      ushort4 va{0, 0, 0, 0}, vb{0, 0, 0, 0};
      if (kg < K) {
        const bf16* srca = (kg < K1) ? A1 + (size_t)(bm + row) * lda1 + kg
                                     : A2 + (size_t)(bm + row) * lda2 + (kg - K1);
        va = *(const ushort4*)srca;
        vb = *(const ushort4*)(W + (size_t)(bn + row) * ldw + kg);
      }
      *(ushort4*)&As[row][q * 4] = va;
      *(ushort4*)&Bs[row][q * 4] = vb;
    }
    __syncthreads();
    bf16x8 af[4], bf_[4];
#pragma unroll
    for (int i = 0; i < 4; ++i)
      af[i] = *(const bf16x8*)&As[wr * 64 + i * 16 + lr][lk];
#pragma unroll
    for (int j = 0; j < 4; ++j)
      bf_[j] = *(const bf16x8*)&Bs[wc * 64 + j * 16 + lr][lk];
#pragma unroll
    for (int i = 0; i < 4; ++i)
#pragma unroll
      for (int j = 0; j < 4; ++j)
        acc[i][j] = __builtin_amdgcn_mfma_f32_16x16x32_bf16(af[i], bf_[j], acc[i][j], 0, 0, 0);
    __syncthreads();
  }
#pragma unroll
  for (int j = 0; j < 4; ++j) {
    int n = bn + wc * 64 + j * 16 + lr;
    float bv = bias ? bias[n] : 0.f;
#pragma unroll
    for (int i = 0; i < 4; ++i) {
#pragma unroll
      for (int p = 0; p < 4; ++p) {
        int m = bm + wr * 64 + i * 16 + (lane >> 4) * 4 + p;
        C[(size_t)m * ldc + n] = __float2bfloat16(acc[i][j][p] + bv);
      }
    }
  }
}

// ---------------------------------------------------------------------------
// features [B,T,FEAT] fp32 -> xT [T,B,FEAT] bf16
// ---------------------------------------------------------------------------
__global__ __launch_bounds__(256) void transpose_feat(
    const float* __restrict__ f, bf16* __restrict__ xT)
{
  const int idx = blockIdx.x * 256 + threadIdx.x;
  const int total = BATCH * T_SEQ * FEATD;
  if (idx >= total) return;
  const int i = idx % FEATD;
  const int r = idx / FEATD;
  const int b = r / T_SEQ;
  const int t = r % T_SEQ;
  xT[((size_t)t * BATCH + b) * FEATD + i] = __float2bfloat16(f[idx]);
}

// ---------------------------------------------------------------------------
// One bidirectional GRU time step, MFMA version.
// xp_*: [T,B,3H] bf16 (x@w_ih^T + b_ih). whh_*: bf16 [3H,H]. out: [T,B,E] bf16.
// 16 blocks: dir(2) x col-tile(8 of 64 hidden cols). 256 threads = 4 waves;
// wave w owns 16 hidden cols x all 3 gates -> gate math is wave-local.
// ---------------------------------------------------------------------------
__global__ __launch_bounds__(256) void gru_step_mfma(
    const bf16* __restrict__ xp_f, const bf16* __restrict__ xp_b,
    const bf16* __restrict__ whh_f, const bf16* __restrict__ whh_b,
    const float* __restrict__ bhh_f, const float* __restrict__ bhh_b,
    bf16* __restrict__ out, int s)
{
  const int dir = blockIdx.x >> 3;
  const int ct  = blockIdx.x & 7;
  const int t   = dir ? (T_SEQ - 1 - s) : s;
  const bf16* xp   = dir ? xp_b  : xp_f;
  const bf16* whh  = dir ? whh_b : whh_f;
  const float* bhh = dir ? bhh_b : bhh_f;
  const int off = dir ? HID : 0;
  const bf16* hprev = nullptr;
  if (s > 0)
    hprev = out + (size_t)(dir ? t + 1 : t - 1) * BATCH * EMB + off;

  const int tid = threadIdx.x;
  const int wave = tid >> 6, lane = tid & 63;
  const int lr = lane & 15, lk = (lane >> 4) << 3;

  __shared__ __bf16 Hs[64][40];    // hprev tile [batch][k32]
  __shared__ __bf16 Ws[192][40];   // whh rows: [gate*64 + ncol][k32]
  f32x4 acc[3][4] = {};            // [gate][m-frag]

  if (s > 0) {
    for (int k0 = 0; k0 < HID; k0 += 32) {
#pragma unroll
      for (int p = 0; p < 2; ++p) {        // 64*8 = 512 quads
        int i = tid + p * 256;
        int row = i >> 3, q = i & 7;
        *(ushort4*)&Hs[row][q * 4] =
            *(const ushort4*)(hprev + (size_t)row * EMB + k0 + q * 4);
      }
#pragma unroll
      for (int p = 0; p < 6; ++p) {        // 192*8 = 1536 quads
        int i = tid + p * 256;
        int row = i >> 3, q = i & 7;
        int g = row >> 6, n = row & 63;
        *(ushort4*)&Ws[row][q * 4] =
            *(const ushort4*)(whh + (size_t)(g * HID + ct * 64 + n) * HID + k0 + q * 4);
      }
      __syncthreads();
      bf16x8 a[4], b[3];
#pragma unroll
      for (int i = 0; i < 4; ++i)
        a[i] = *(const bf16x8*)&Hs[i * 16 + lr][lk];
#pragma unroll
      for (int g = 0; g < 3; ++g)
        b[g] = *(const bf16x8*)&Ws[g * 64 + wave * 16 + lr][lk];
#pragma unroll
      for (int g = 0; g < 3; ++g)
#pragma unroll
        for (int i = 0; i < 4; ++i)
          acc[g][i] = __builtin_amdgcn_mfma_f32_16x16x32_bf16(a[i], b[g], acc[g][i], 0, 0, 0);
      __syncthreads();
    }
  }

  const int c = ct * 64 + wave * 16 + lr;      // hidden col (0..511)
  const float bhr = bhh[c], bhz = bhh[HID + c], bhn = bhh[2 * HID + c];
  const size_t xbase = (size_t)t * BATCH * G3;
  const size_t obase = (size_t)t * BATCH * EMB + off;
#pragma unroll
  for (int i = 0; i < 4; ++i) {
#pragma unroll
    for (int p = 0; p < 4; ++p) {
      int m = i * 16 + (lane >> 4) * 4 + p;
      const size_t xrow = xbase + (size_t)m * G3;
      float xr = __bfloat162float(xp[xrow + c]);
      float xz = __bfloat162float(xp[xrow + HID + c]);
      float xn = __bfloat162float(xp[xrow + 2 * HID + c]);
      float hr = acc[0][i][p] + bhr;
      float hz = acc[1][i][p] + bhz;
      float hn = acc[2][i][p] + bhn;
      float hp = (s > 0) ? __bfloat162float(hprev[(size_t)m * EMB + c]) : 0.f;
      float r = 1.f / (1.f + expf(-(xr + hr)));
      float z = 1.f / (1.f + expf(-(xz + hz)));
      float n = tanhf(xn + r * hn);
      out[obase + (size_t)m * EMB + c] = __float2bfloat16((1.f - z) * n + z * hp);
    }
  }
}

// ---------------------------------------------------------------------------
// K/V projections: ne batch-broadcast -> K/V collapse to [NT, EMB] fp32.
// ---------------------------------------------------------------------------
__global__ __launch_bounds__(256) void kv_kernel(
    const float* __restrict__ ne, const float* __restrict__ k_w,
    const float* __restrict__ k_b, const float* __restrict__ v_w,
    const float* __restrict__ v_b, float* __restrict__ kk,
    float* __restrict__ vv)
{
  const int e = blockIdx.x * 256 + threadIdx.x;
  if (e >= EMB) return;
#pragma unroll
  for (int s = 0; s < NTAG; ++s) {
    float a = k_b[e], c = v_b[e];
#pragma unroll
    for (int i = 0; i < NTAG; ++i) {
      float nv = ne[s * NTAG + i];
      a = fmaf(nv, k_w[e * NTAG + i], a);
      c = fmaf(nv, v_w[e * NTAG + i], c);
    }
    kk[s * EMB + e] = a;
    vv[s * EMB + e] = c;
  }
}

// ---------------------------------------------------------------------------
// Attention: 4 (tb,head) units per 256-thread block. S=14 keys, HD=128.
// ---------------------------------------------------------------------------
__global__ __launch_bounds__(256) void attn_kernel(
    const bf16* __restrict__ q, const float* __restrict__ kk,
    const float* __restrict__ vv, bf16* __restrict__ ao)
{
  const int unit = blockIdx.x * 4 + (threadIdx.x >> 6);
  const int h = unit & 7;
  const int tb = unit >> 3;
  const int lane = threadIdx.x & 63;
  const size_t qbase = (size_t)tb * EMB + h * 128;
  const int kbase = h * 128 + lane;
  float q0 = __bfloat162float(q[qbase + lane]);
  float q1 = __bfloat162float(q[qbase + 64 + lane]);
  float sc[NTAG];
#pragma unroll
  for (int j = 0; j < NTAG; ++j) {
    float p = q0 * kk[j * EMB + kbase] + q1 * kk[j * EMB + 64 + kbase];
#pragma unroll
    for (int d = 32; d; d >>= 1) p += __shfl_xor(p, d);
    sc[j] = p * 0.088388347648318447f;  // 1/sqrt(128)
  }
  float m = sc[0];
#pragma unroll
  for (int j = 1; j < NTAG; ++j) m = fmaxf(m, sc[j]);
  float sum = 0.f;
#pragma unroll
  for (int j = 0; j < NTAG; ++j) { sc[j] = expf(sc[j] - m); sum += sc[j]; }
  float inv = 1.f / sum;
  float o0 = 0.f, o1 = 0.f;
#pragma unroll
  for (int j = 0; j < NTAG; ++j) {
    float p = sc[j] * inv;
    o0 = fmaf(p, vv[j * EMB + kbase], o0);
    o1 = fmaf(p, vv[j * EMB + 64 + kbase], o1);
  }
  ao[qbase + lane] = __float2bfloat16(o0);
  ao[qbase + 64 + lane] = __float2bfloat16(o1);
}

// ---------------------------------------------------------------------------
// Fused final linear + ne-table logits: 4 (t,b) units per block.
// dec [T,B,EMB] bf16 -> logits [B,T,NT] fp32
// ---------------------------------------------------------------------------
__global__ __launch_bounds__(256) void dec_logits_kernel(
    const bf16* __restrict__ dec, const float* __restrict__ lin_w,
    const float* __restrict__ lin_b, const float* __restrict__ ne,
    float* __restrict__ logits)
{
  const int tb = blockIdx.x * 4 + (threadIdx.x >> 6);
  const int t = tb >> 6;   // /BATCH
  const int b = tb & 63;
  const int lane = threadIdx.x & 63;
  const bf16* drow = dec + (size_t)tb * EMB;
  float dv[16];
#pragma unroll
  for (int i = 0; i < 16; ++i) dv[i] = __bfloat162float(drow[lane + 64 * i]);
  float dl[NTAG];
#pragma unroll
  for (int n = 0; n < NTAG; ++n) {
    float p = 0.f;
#pragma unroll
    for (int i = 0; i < 16; ++i)
      p = fmaf(dv[i], lin_w[n * EMB + lane + 64 * i], p);
#pragma unroll
    for (int d = 32; d; d >>= 1) p += __shfl_xor(p, d);
    dl[n] = p + lin_b[n];
  }
  if (lane < NTAG) {
    float acc = 0.f;
#pragma unroll
    for (int d2 = 0; d2 < NTAG; ++d2)
      acc = fmaf(dl[d2], ne[lane * NTAG + d2], acc);
    logits[((size_t)b * T_SEQ + t) * NTAG + lane] = acc * 0.26726124191242439f; // 1/sqrt(14)
  }
}

// ---------------------------------------------------------------------------
// CRF NLL per batch element (one wave per b; alpha recurrence over T).
// ---------------------------------------------------------------------------
__global__ __launch_bounds__(64) void crf_kernel(
    const float* __restrict__ logits, const int* __restrict__ labels,
    const float* __restrict__ cstart, const float* __restrict__ cend,
    const float* __restrict__ ctrans, float* __restrict__ lossb)
{
  const int b = blockIdx.x;
  const int lane = threadIdx.x;
  __shared__ float al[NTAG];
  __shared__ float tr[NTAG * NTAG];
  __shared__ float tmp[NTAG];
  const float* lg = logits + (size_t)b * T_SEQ * NTAG;
  const int* lab = labels + (size_t)b * T_SEQ;
  for (int i = lane; i < NTAG * NTAG; i += 64) tr[i] = ctrans[i];
  if (lane < NTAG) al[lane] = cstart[lane] + lg[lane];
  __syncthreads();
  for (int t = 1; t < T_SEQ; ++t) {
    float v = 0.f;
    if (lane < NTAG) {
      float mx = -1e30f;
#pragma unroll
      for (int i = 0; i < NTAG; ++i) mx = fmaxf(mx, al[i] + tr[i * NTAG + lane]);
      float sm = 0.f;
#pragma unroll
      for (int i = 0; i < NTAG; ++i) sm += expf(al[i] + tr[i * NTAG + lane] - mx);
      v = mx + logf(sm) + lg[t * NTAG + lane];
    }
    __syncthreads();
    if (lane < NTAG) al[lane] = v;
    __syncthreads();
  }
  float em = 0.f;
  for (int t = lane; t < T_SEQ; t += 64) em += lg[t * NTAG + lab[t]];
  float trs = 0.f;
  for (int t = lane; t < T_SEQ - 1; t += 64) trs += tr[lab[t] * NTAG + lab[t + 1]];
  float p = em + trs;
#pragma unroll
  for (int d = 32; d; d >>= 1) p += __shfl_xor(p, d);
  if (lane < NTAG) tmp[lane] = al[lane] + cend[lane];
  __syncthreads();
  if (lane == 0) {
    float num = p + cstart[lab[0]] + cend[lab[T_SEQ - 1]];
    float mx = tmp[0];
#pragma unroll
    for (int i = 1; i < NTAG; ++i) mx = fmaxf(mx, tmp[i]);
    float sm = 0.f;
#pragma unroll
    for (int i = 0; i < NTAG; ++i) sm += expf(tmp[i] - mx);
    float den = mx + logf(sm);
    lossb[b] = -(num - den);
  }
}

__global__ __launch_bounds__(64) void final_reduce(
    const float* __restrict__ lossb, float* __restrict__ out)
{
  float v = lossb[threadIdx.x];
#pragma unroll
  for (int d = 32; d; d >>= 1) v += __shfl_xor(v, d);
  if (threadIdx.x == 0) out[0] = v * (1.f / 64.f);
}

// ---------------------------------------------------------------------------
extern "C" void kernel_launch(void* const* d_in, const int* in_sizes, int n_in,
                              void* d_out, int out_size, void* d_ws, size_t ws_size,
                              hipStream_t stream)
{
  const float* features = (const float*)d_in[0];
  const int*   labels   = (const int*)d_in[1];
  const float* ne_table = (const float*)d_in[2];
  const float* g1_wih_f = (const float*)d_in[3];
  const float* g1_whh_f = (const float*)d_in[4];
  const float* g1_bih_f = (const float*)d_in[5];
  const float* g1_bhh_f = (const float*)d_in[6];
  const float* g1_wih_b = (const float*)d_in[7];
  const float* g1_whh_b = (const float*)d_in[8];
  const float* g1_bih_b = (const float*)d_in[9];
  const float* g1_bhh_b = (const float*)d_in[10];
  const float* g2_wih_f = (const float*)d_in[11];
  const float* g2_whh_f = (const float*)d_in[12];
  const float* g2_bih_f = (const float*)d_in[13];
  const float* g2_bhh_f = (const float*)d_in[14];
  const float* g2_wih_b = (const float*)d_in[15];
  const float* g2_whh_b = (const float*)d_in[16];
  const float* g2_bih_b = (const float*)d_in[17];
  const float* g2_bhh_b = (const float*)d_in[18];
  const float* q_w   = (const float*)d_in[19];
  const float* q_b   = (const float*)d_in[20];
  const float* k_w   = (const float*)d_in[21];
  const float* k_b   = (const float*)d_in[22];
  const float* v_w   = (const float*)d_in[23];
  const float* v_b   = (const float*)d_in[24];
  const float* out_w = (const float*)d_in[25];
  const float* out_b = (const float*)d_in[26];
  const float* lin_w = (const float*)d_in[27];
  const float* lin_b = (const float*)d_in[28];
  const float* crf_start = (const float*)d_in[29];
  const float* crf_end   = (const float*)d_in[30];
  const float* crf_trans = (const float*)d_in[31];

  // ---- workspace layout (~218 MB) ----
  const size_t NTB = (size_t)T_SEQ * BATCH;      // 16384
  char* base = (char*)d_ws;
  size_t off = 0;
  auto alloc = [&](size_t bytes) {
    char* p = base + off;
    off += (bytes + 255) & ~(size_t)255;
    return p;
  };
  bf16* xpA  = (bf16*)alloc(NTB * G3 * sizeof(bf16));   // xp fwd (gru1, then gru2)
  bf16* xpB  = (bf16*)alloc(NTB * G3 * sizeof(bf16));   // xp bwd
  bf16* enc  = (bf16*)alloc(NTB * EMB * sizeof(bf16));  // gru1 output
  bf16* bufD = (bf16*)alloc(NTB * EMB * sizeof(bf16));  // xT -> aoraw -> dec
  bf16* bufE = (bf16*)alloc(NTB * EMB * sizeof(bf16));  // q -> aofin
  float* kkbuf  = (float*)alloc((size_t)NTAG * EMB * sizeof(float));
  float* vvbuf  = (float*)alloc((size_t)NTAG * EMB * sizeof(float));
  float* logits = (float*)alloc(NTB * NTAG * sizeof(float));
  float* lossb  = (float*)alloc(64 * sizeof(float));
  // bf16 weight copies (~24.2 MB)
  bf16* w1if = (bf16*)alloc((size_t)G3 * FEATD * sizeof(bf16));
  bf16* w1ib = (bf16*)alloc((size_t)G3 * FEATD * sizeof(bf16));
  bf16* w1hf = (bf16*)alloc((size_t)G3 * HID * sizeof(bf16));
  bf16* w1hb = (bf16*)alloc((size_t)G3 * HID * sizeof(bf16));
  bf16* w2if = (bf16*)alloc((size_t)G3 * 2 * EMB * sizeof(bf16));
  bf16* w2ib = (bf16*)alloc((size_t)G3 * 2 * EMB * sizeof(bf16));
  bf16* w2hf = (bf16*)alloc((size_t)G3 * HID * sizeof(bf16));
  bf16* w2hb = (bf16*)alloc((size_t)G3 * HID * sizeof(bf16));
  bf16* wq   = (bf16*)alloc((size_t)EMB * EMB * sizeof(bf16));
  bf16* wo   = (bf16*)alloc((size_t)EMB * EMB * sizeof(bf16));
  (void)off; (void)ws_size; (void)in_sizes; (void)n_in; (void)out_size;

  bf16* xT = bufD;  // [T,B,FEAT] bf16, aliases bufD (dead before aoraw)

  const int M = (int)NTB;  // 16384
  dim3 blk(256);

  // 0. weight conversions fp32 -> bf16
  auto conv = [&](const float* s, bf16* d, size_t n) {
    f32_to_bf16<<<(int)((n / 4 + 255) / 256), blk, 0, stream>>>(s, d, (int)(n / 4));
  };
  conv(g1_wih_f, w1if, (size_t)G3 * FEATD);
  conv(g1_wih_b, w1ib, (size_t)G3 * FEATD);
  conv(g1_whh_f, w1hf, (size_t)G3 * HID);
  conv(g1_whh_b, w1hb, (size_t)G3 * HID);
  conv(g2_wih_f, w2if, (size_t)G3 * 2 * EMB);
  conv(g2_wih_b, w2ib, (size_t)G3 * 2 * EMB);
  conv(g2_whh_f, w2hf, (size_t)G3 * HID);
  conv(g2_whh_b, w2hb, (size_t)G3 * HID);
  conv(q_w, wq, (size_t)EMB * EMB);
  conv(out_w, wo, (size_t)EMB * EMB);

  // 1. features -> [T,B,FEAT] bf16
  transpose_feat<<<(BATCH * T_SEQ * FEATD + 255) / 256, blk, 0, stream>>>(features, xT);

  dim3 g_xp(G3 / 128, M / 128);   // (12,128)
  dim3 g_e(EMB / 128, M / 128);   // (8,128)

  // 2. GRU1 input projections
  gemm_mfma<<<g_xp, blk, 0, stream>>>(xT, FEATD, nullptr, 0, FEATD,
                                      w1if, FEATD, g1_bih_f, xpA, G3, M, G3, FEATD);
  gemm_mfma<<<g_xp, blk, 0, stream>>>(xT, FEATD, nullptr, 0, FEATD,
                                      w1ib, FEATD, g1_bih_b, xpB, G3, M, G3, FEATD);

  // 3. GRU1 recurrence -> enc
  for (int s = 0; s < T_SEQ; ++s)
    gru_step_mfma<<<16, blk, 0, stream>>>(xpA, xpB, w1hf, w1hb, g1_bhh_f, g1_bhh_b, enc, s);

  // 4. K/V (batch-independent) + Q projection -> bufE
  kv_kernel<<<4, blk, 0, stream>>>(ne_table, k_w, k_b, v_w, v_b, kkbuf, vvbuf);
  gemm_mfma<<<g_e, blk, 0, stream>>>(enc, EMB, nullptr, 0, EMB,
                                     wq, EMB, q_b, bufE, EMB, M, EMB, EMB);

  // 5. Attention (q=bufE -> aoraw=bufD) + output projection (-> aofin=bufE)
  attn_kernel<<<M * 2, blk, 0, stream>>>(bufE, kkbuf, vvbuf, bufD);
  gemm_mfma<<<g_e, blk, 0, stream>>>(bufD, EMB, nullptr, 0, EMB,
                                     wo, EMB, out_b, bufE, EMB, M, EMB, EMB);

  // 6. GRU2 input projections: dec_in = [enc, ao] via concat-A GEMM
  gemm_mfma<<<g_xp, blk, 0, stream>>>(enc, EMB, bufE, EMB, EMB,
                                      w2if, 2 * EMB, g2_bih_f, xpA, G3, M, G3, 2 * EMB);
  gemm_mfma<<<g_xp, blk, 0, stream>>>(enc, EMB, bufE, EMB, EMB,
                                      w2ib, 2 * EMB, g2_bih_b, xpB, G3, M, G3, 2 * EMB);

  // 7. GRU2 recurrence -> dec (bufD; aoraw dead)
  for (int s = 0; s < T_SEQ; ++s)
    gru_step_mfma<<<16, blk, 0, stream>>>(xpA, xpB, w2hf, w2hb, g2_bhh_f, g2_bhh_b, bufD, s);

  // 8. Final linear + ne logits
  dec_logits_kernel<<<M / 4, blk, 0, stream>>>(bufD, lin_w, lin_b, ne_table, logits);

  // 9. CRF NLL + mean
  crf_kernel<<<BATCH, 64, 0, stream>>>(logits, labels, crf_start, crf_end, crf_trans, lossb);
  final_reduce<<<1, 64, 0, stream>>>(lossb, (float*)d_out);
}

// Round 5
// 7656.899 us; speedup vs baseline: 8.0928x; 1.5121x over previous
//
#include <hip/hip_runtime.h>
#include <hip/hip_bf16.h>
#include <math.h>

typedef __hip_bfloat16 bf16;
typedef __bf16 bf16x8 __attribute__((ext_vector_type(8)));
typedef float  f32x4  __attribute__((ext_vector_type(4)));

#define T_SEQ 256
#define BATCH 64
#define FEATD 188
#define HID   512
#define EMB   1024
#define NTAG  14
#define G3    1536   // 3*HID
#define GRU_NBLK 32  // 16 blocks/dir, 32 hidden cols each

// ---------------------------------------------------------------------------
// fp32 -> bf16 weight conversion (vectorized x4; all n % 4 == 0)
// ---------------------------------------------------------------------------
__global__ __launch_bounds__(256) void f32_to_bf16(
    const float* __restrict__ src, bf16* __restrict__ dst, int n4)
{
  int i = blockIdx.x * 256 + threadIdx.x;
  if (i >= n4) return;
  float4 v = *(const float4*)(src + (size_t)i * 4);
  bf16 o[4] = {__float2bfloat16(v.x), __float2bfloat16(v.y),
               __float2bfloat16(v.z), __float2bfloat16(v.w)};
  *(ushort4*)(dst + (size_t)i * 4) = *(ushort4*)o;
}

// ---------------------------------------------------------------------------
// MFMA GEMM: C[M,N] = concat(A1,A2)[M,K] @ W[N,K]^T + bias. (validated R3)
// ---------------------------------------------------------------------------
__global__ __launch_bounds__(256) void gemm_mfma(
    const bf16* __restrict__ A1, int lda1,
    const bf16* __restrict__ A2, int lda2, int K1,
    const bf16* __restrict__ W, int ldw,
    const float* __restrict__ bias,
    bf16* __restrict__ C, int ldc,
    int M, int N, int K)
{
  __shared__ __bf16 As[128][40];
  __shared__ __bf16 Bs[128][40];
  const int bm = blockIdx.y * 128;
  const int bn = blockIdx.x * 128;
  const int tid = threadIdx.x;
  const int wave = tid >> 6, lane = tid & 63;
  const int wr = wave >> 1, wc = wave & 1;
  const int lr = lane & 15, lk = (lane >> 4) << 3;
  f32x4 acc[4][4] = {};
  for (int k0 = 0; k0 < K; k0 += 32) {
#pragma unroll
    for (int p = 0; p < 4; ++p) {
      int i = tid + p * 256;
      int row = i >> 3, q = i & 7;
      int kg = k0 + q * 4;
      ushort4 va{0, 0, 0, 0}, vb{0, 0, 0, 0};
      if (kg < K) {
        const bf16* srca = (kg < K1) ? A1 + (size_t)(bm + row) * lda1 + kg
                                     : A2 + (size_t)(bm + row) * lda2 + (kg - K1);
        va = *(const ushort4*)srca;
        vb = *(const ushort4*)(W + (size_t)(bn + row) * ldw + kg);
      }
      *(ushort4*)&As[row][q * 4] = va;
      *(ushort4*)&Bs[row][q * 4] = vb;
    }
    __syncthreads();
    bf16x8 af[4], bf_[4];
#pragma unroll
    for (int i = 0; i < 4; ++i)
      af[i] = *(const bf16x8*)&As[wr * 64 + i * 16 + lr][lk];
#pragma unroll
    for (int j = 0; j < 4; ++j)
      bf_[j] = *(const bf16x8*)&Bs[wc * 64 + j * 16 + lr][lk];
#pragma unroll
    for (int i = 0; i < 4; ++i)
#pragma unroll
      for (int j = 0; j < 4; ++j)
        acc[i][j] = __builtin_amdgcn_mfma_f32_16x16x32_bf16(af[i], bf_[j], acc[i][j], 0, 0, 0);
    __syncthreads();
  }
#pragma unroll
  for (int j = 0; j < 4; ++j) {
    int n = bn + wc * 64 + j * 16 + lr;
    float bv = bias ? bias[n] : 0.f;
#pragma unroll
    for (int i = 0; i < 4; ++i) {
#pragma unroll
      for (int p = 0; p < 4; ++p) {
        int m = bm + wr * 64 + i * 16 + (lane >> 4) * 4 + p;
        C[(size_t)m * ldc + n] = __float2bfloat16(acc[i][j][p] + bv);
      }
    }
  }
}

// ---------------------------------------------------------------------------
// features [B,T,FEAT] fp32 -> xT [T,B,FEAT] bf16
// ---------------------------------------------------------------------------
__global__ __launch_bounds__(256) void transpose_feat(
    const float* __restrict__ f, bf16* __restrict__ xT)
{
  const int idx = blockIdx.x * 256 + threadIdx.x;
  const int total = BATCH * T_SEQ * FEATD;
  if (idx >= total) return;
  const int i = idx % FEATD;
  const int r = idx / FEATD;
  const int b = r / T_SEQ;
  const int t = r % T_SEQ;
  xT[((size_t)t * BATCH + b) * FEATD + i] = __float2bfloat16(f[idx]);
}

// ---------------------------------------------------------------------------
// Persistent bidirectional GRU layer: ONE launch does all 256 timesteps.
// 32 blocks (dir x 16 col-tiles of 32 hidden cols), 256 threads = 4 waves.
// Block's 96x512 weight slice lives in LDS for the whole kernel.
// Per step: MFMA (A = h_prev from global, B = weights from LDS), gate math,
// store h(t), then device-scope grid barrier (fresh counter per step,
// counters zeroed by host memset each launch -> graph-replay deterministic).
// ---------------------------------------------------------------------------
__global__ __launch_bounds__(256) void gru_persist(
    const bf16* __restrict__ xp_f, const bf16* __restrict__ xp_b,
    const bf16* __restrict__ whh_f, const bf16* __restrict__ whh_b,
    const float* __restrict__ bhh_f, const float* __restrict__ bhh_b,
    bf16* __restrict__ out, int* __restrict__ cnt)
{
  const int blk = blockIdx.x;
  const int dir = blk >> 4;
  const int ct  = blk & 15;
  const bf16* xp   = dir ? xp_b  : xp_f;
  const bf16* whh  = dir ? whh_b : whh_f;
  const float* bhh = dir ? bhh_b : bhh_f;
  const int off = dir ? HID : 0;
  const int tid = threadIdx.x;
  const int wave = tid >> 6, lane = tid & 63;
  const int lr = lane & 15, lkq = lane >> 4;

  // weights: rows r = g*32 + n  (g gate, n local col), padded stride 520
  // (row stride 1040 B = 65*16 -> 16B-aligned, 2-way bank conflict = free)
  __shared__ __bf16 Ws[96][520];
  // FIX (R4 bug): 16-byte copies — float4 = 8 bf16; q in 0..63 covers all 512.
  for (int i = tid; i < 96 * 64; i += 256) {
    int r = i >> 6, q = i & 63;
    int grow = (r >> 5) * HID + ct * 32 + (r & 31);
    *(float4*)&Ws[r][q * 8] = *(const float4*)(whh + (size_t)grow * HID + q * 8);
  }
  __syncthreads();

  float bh[3][2];
#pragma unroll
  for (int g = 0; g < 3; ++g)
#pragma unroll
    for (int nf = 0; nf < 2; ++nf)
      bh[g][nf] = bhh[g * HID + ct * 32 + nf * 16 + lr];

  for (int s = 0; s < T_SEQ; ++s) {
    const int t = dir ? (T_SEQ - 1 - s) : s;
    const bf16* hprev = out + (size_t)(dir ? t + 1 : t - 1) * BATCH * EMB + off;
    f32x4 acc[3][2] = {};
    if (s > 0) {
      const bf16* arow = hprev + (size_t)(wave * 16 + lr) * EMB + lkq * 8;
#pragma unroll
      for (int ki = 0; ki < 16; ++ki) {
        bf16x8 a = *(const bf16x8*)(arow + ki * 32);
#pragma unroll
        for (int g = 0; g < 3; ++g)
#pragma unroll
          for (int nf = 0; nf < 2; ++nf) {
            bf16x8 b = *(const bf16x8*)&Ws[g * 32 + nf * 16 + lr][ki * 32 + lkq * 8];
            acc[g][nf] = __builtin_amdgcn_mfma_f32_16x16x32_bf16(a, b, acc[g][nf], 0, 0, 0);
          }
      }
    }
    const size_t xbase = (size_t)t * BATCH * G3;
    const size_t obase = (size_t)t * BATCH * EMB + off;
#pragma unroll
    for (int nf = 0; nf < 2; ++nf) {
      const int c = ct * 32 + nf * 16 + lr;
#pragma unroll
      for (int p = 0; p < 4; ++p) {
        const int m = wave * 16 + lkq * 4 + p;
        const size_t xrow = xbase + (size_t)m * G3;
        float xr = __bfloat162float(xp[xrow + c]);
        float xz = __bfloat162float(xp[xrow + HID + c]);
        float xn = __bfloat162float(xp[xrow + 2 * HID + c]);
        float hr = acc[0][nf][p] + bh[0][nf];
        float hz = acc[1][nf][p] + bh[1][nf];
        float hn = acc[2][nf][p] + bh[2][nf];
        float hp = (s > 0) ? __bfloat162float(hprev[(size_t)m * EMB + c]) : 0.f;
        float r = 1.f / (1.f + expf(-(xr + hr)));
        float z = 1.f / (1.f + expf(-(xz + hz)));
        float n = tanhf(xn + r * hn);
        out[obase + (size_t)m * EMB + c] = __float2bfloat16((1.f - z) * n + z * hp);
      }
    }
    // ---- device-scope grid barrier over GRU_NBLK blocks (step s) ----
    __threadfence();                 // make my h(t) stores visible device-wide
    __syncthreads();                 // whole block done
    if (tid == 0) {
      __hip_atomic_fetch_add(&cnt[s], 1, __ATOMIC_RELEASE, __HIP_MEMORY_SCOPE_AGENT);
      while (__hip_atomic_load(&cnt[s], __ATOMIC_RELAXED, __HIP_MEMORY_SCOPE_AGENT) < GRU_NBLK)
        __builtin_amdgcn_s_sleep(1);
    }
    __syncthreads();
    __threadfence();                 // acquire: discard stale cached h
  }
}

// ---------------------------------------------------------------------------
// K/V projections: ne batch-broadcast -> K/V collapse to [NT, EMB] fp32.
// ---------------------------------------------------------------------------
__global__ __launch_bounds__(256) void kv_kernel(
    const float* __restrict__ ne, const float* __restrict__ k_w,
    const float* __restrict__ k_b, const float* __restrict__ v_w,
    const float* __restrict__ v_b, float* __restrict__ kk,
    float* __restrict__ vv)
{
  const int e = blockIdx.x * 256 + threadIdx.x;
  if (e >= EMB) return;
#pragma unroll
  for (int s = 0; s < NTAG; ++s) {
    float a = k_b[e], c = v_b[e];
#pragma unroll
    for (int i = 0; i < NTAG; ++i) {
      float nv = ne[s * NTAG + i];
      a = fmaf(nv, k_w[e * NTAG + i], a);
      c = fmaf(nv, v_w[e * NTAG + i], c);
    }
    kk[s * EMB + e] = a;
    vv[s * EMB + e] = c;
  }
}

// ---------------------------------------------------------------------------
// Attention: 4 (tb,head) units per 256-thread block. S=14 keys, HD=128.
// ---------------------------------------------------------------------------
__global__ __launch_bounds__(256) void attn_kernel(
    const bf16* __restrict__ q, const float* __restrict__ kk,
    const float* __restrict__ vv, bf16* __restrict__ ao)
{
  const int unit = blockIdx.x * 4 + (threadIdx.x >> 6);
  const int h = unit & 7;
  const int tb = unit >> 3;
  const int lane = threadIdx.x & 63;
  const size_t qbase = (size_t)tb * EMB + h * 128;
  const int kbase = h * 128 + lane;
  float q0 = __bfloat162float(q[qbase + lane]);
  float q1 = __bfloat162float(q[qbase + 64 + lane]);
  float sc[NTAG];
#pragma unroll
  for (int j = 0; j < NTAG; ++j) {
    float p = q0 * kk[j * EMB + kbase] + q1 * kk[j * EMB + 64 + kbase];
#pragma unroll
    for (int d = 32; d; d >>= 1) p += __shfl_xor(p, d);
    sc[j] = p * 0.088388347648318447f;  // 1/sqrt(128)
  }
  float m = sc[0];
#pragma unroll
  for (int j = 1; j < NTAG; ++j) m = fmaxf(m, sc[j]);
  float sum = 0.f;
#pragma unroll
  for (int j = 0; j < NTAG; ++j) { sc[j] = expf(sc[j] - m); sum += sc[j]; }
  float inv = 1.f / sum;
  float o0 = 0.f, o1 = 0.f;
#pragma unroll
  for (int j = 0; j < NTAG; ++j) {
    float p = sc[j] * inv;
    o0 = fmaf(p, vv[j * EMB + kbase], o0);
    o1 = fmaf(p, vv[j * EMB + 64 + kbase], o1);
  }
  ao[qbase + lane] = __float2bfloat16(o0);
  ao[qbase + 64 + lane] = __float2bfloat16(o1);
}

// ---------------------------------------------------------------------------
// Fused final linear + ne-table logits: 4 (t,b) units per block.
// ---------------------------------------------------------------------------
__global__ __launch_bounds__(256) void dec_logits_kernel(
    const bf16* __restrict__ dec, const float* __restrict__ lin_w,
    const float* __restrict__ lin_b, const float* __restrict__ ne,
    float* __restrict__ logits)
{
  const int tb = blockIdx.x * 4 + (threadIdx.x >> 6);
  const int t = tb >> 6;
  const int b = tb & 63;
  const int lane = threadIdx.x & 63;
  const bf16* drow = dec + (size_t)tb * EMB;
  float dv[16];
#pragma unroll
  for (int i = 0; i < 16; ++i) dv[i] = __bfloat162float(drow[lane + 64 * i]);
  float dl[NTAG];
#pragma unroll
  for (int n = 0; n < NTAG; ++n) {
    float p = 0.f;
#pragma unroll
    for (int i = 0; i < 16; ++i)
      p = fmaf(dv[i], lin_w[n * EMB + lane + 64 * i], p);
#pragma unroll
    for (int d = 32; d; d >>= 1) p += __shfl_xor(p, d);
    dl[n] = p + lin_b[n];
  }
  if (lane < NTAG) {
    float acc = 0.f;
#pragma unroll
    for (int d2 = 0; d2 < NTAG; ++d2)
      acc = fmaf(dl[d2], ne[lane * NTAG + d2], acc);
    logits[((size_t)b * T_SEQ + t) * NTAG + lane] = acc * 0.26726124191242439f; // 1/sqrt(14)
  }
}

// ---------------------------------------------------------------------------
// CRF NLL per batch element (one wave per b; alpha recurrence over T).
// ---------------------------------------------------------------------------
__global__ __launch_bounds__(64) void crf_kernel(
    const float* __restrict__ logits, const int* __restrict__ labels,
    const float* __restrict__ cstart, const float* __restrict__ cend,
    const float* __restrict__ ctrans, float* __restrict__ lossb)
{
  const int b = blockIdx.x;
  const int lane = threadIdx.x;
  __shared__ float al[NTAG];
  __shared__ float tr[NTAG * NTAG];
  __shared__ float tmp[NTAG];
  const float* lg = logits + (size_t)b * T_SEQ * NTAG;
  const int* lab = labels + (size_t)b * T_SEQ;
  for (int i = lane; i < NTAG * NTAG; i += 64) tr[i] = ctrans[i];
  if (lane < NTAG) al[lane] = cstart[lane] + lg[lane];
  __syncthreads();
  for (int t = 1; t < T_SEQ; ++t) {
    float v = 0.f;
    if (lane < NTAG) {
      float mx = -1e30f;
#pragma unroll
      for (int i = 0; i < NTAG; ++i) mx = fmaxf(mx, al[i] + tr[i * NTAG + lane]);
      float sm = 0.f;
#pragma unroll
      for (int i = 0; i < NTAG; ++i) sm += expf(al[i] + tr[i * NTAG + lane] - mx);
      v = mx + logf(sm) + lg[t * NTAG + lane];
    }
    __syncthreads();
    if (lane < NTAG) al[lane] = v;
    __syncthreads();
  }
  float em = 0.f;
  for (int t = lane; t < T_SEQ; t += 64) em += lg[t * NTAG + lab[t]];
  float trs = 0.f;
  for (int t = lane; t < T_SEQ - 1; t += 64) trs += tr[lab[t] * NTAG + lab[t + 1]];
  float p = em + trs;
#pragma unroll
  for (int d = 32; d; d >>= 1) p += __shfl_xor(p, d);
  if (lane < NTAG) tmp[lane] = al[lane] + cend[lane];
  __syncthreads();
  if (lane == 0) {
    float num = p + cstart[lab[0]] + cend[lab[T_SEQ - 1]];
    float mx = tmp[0];
#pragma unroll
    for (int i = 1; i < NTAG; ++i) mx = fmaxf(mx, tmp[i]);
    float sm = 0.f;
#pragma unroll
    for (int i = 0; i < NTAG; ++i) sm += expf(tmp[i] - mx);
    float den = mx + logf(sm);
    lossb[b] = -(num - den);
  }
}

__global__ __launch_bounds__(64) void final_reduce(
    const float* __restrict__ lossb, float* __restrict__ out)
{
  float v = lossb[threadIdx.x];
#pragma unroll
  for (int d = 32; d; d >>= 1) v += __shfl_xor(v, d);
  if (threadIdx.x == 0) out[0] = v * (1.f / 64.f);
}

// ---------------------------------------------------------------------------
extern "C" void kernel_launch(void* const* d_in, const int* in_sizes, int n_in,
                              void* d_out, int out_size, void* d_ws, size_t ws_size,
                              hipStream_t stream)
{
  const float* features = (const float*)d_in[0];
  const int*   labels   = (const int*)d_in[1];
  const float* ne_table = (const float*)d_in[2];
  const float* g1_wih_f = (const float*)d_in[3];
  const float* g1_whh_f = (const float*)d_in[4];
  const float* g1_bih_f = (const float*)d_in[5];
  const float* g1_bhh_f = (const float*)d_in[6];
  const float* g1_wih_b = (const float*)d_in[7];
  const float* g1_whh_b = (const float*)d_in[8];
  const float* g1_bih_b = (const float*)d_in[9];
  const float* g1_bhh_b = (const float*)d_in[10];
  const float* g2_wih_f = (const float*)d_in[11];
  const float* g2_whh_f = (const float*)d_in[12];
  const float* g2_bih_f = (const float*)d_in[13];
  const float* g2_bhh_f = (const float*)d_in[14];
  const float* g2_wih_b = (const float*)d_in[15];
  const float* g2_whh_b = (const float*)d_in[16];
  const float* g2_bih_b = (const float*)d_in[17];
  const float* g2_bhh_b = (const float*)d_in[18];
  const float* q_w   = (const float*)d_in[19];
  const float* q_b   = (const float*)d_in[20];
  const float* k_w   = (const float*)d_in[21];
  const float* k_b   = (const float*)d_in[22];
  const float* v_w   = (const float*)d_in[23];
  const float* v_b   = (const float*)d_in[24];
  const float* out_w = (const float*)d_in[25];
  const float* out_b = (const float*)d_in[26];
  const float* lin_w = (const float*)d_in[27];
  const float* lin_b = (const float*)d_in[28];
  const float* crf_start = (const float*)d_in[29];
  const float* crf_end   = (const float*)d_in[30];
  const float* crf_trans = (const float*)d_in[31];

  // ---- workspace layout (~218 MB) ----
  const size_t NTB = (size_t)T_SEQ * BATCH;      // 16384
  char* base = (char*)d_ws;
  size_t off = 0;
  auto alloc = [&](size_t bytes) {
    char* p = base + off;
    off += (bytes + 255) & ~(size_t)255;
    return p;
  };
  bf16* xpA  = (bf16*)alloc(NTB * G3 * sizeof(bf16));   // xp fwd (gru1, then gru2)
  bf16* xpB  = (bf16*)alloc(NTB * G3 * sizeof(bf16));   // xp bwd
  bf16* enc  = (bf16*)alloc(NTB * EMB * sizeof(bf16));  // gru1 output
  bf16* bufD = (bf16*)alloc(NTB * EMB * sizeof(bf16));  // xT -> aoraw -> dec
  bf16* bufE = (bf16*)alloc(NTB * EMB * sizeof(bf16));  // q -> aofin
  float* kkbuf  = (float*)alloc((size_t)NTAG * EMB * sizeof(float));
  float* vvbuf  = (float*)alloc((size_t)NTAG * EMB * sizeof(float));
  float* logits = (float*)alloc(NTB * NTAG * sizeof(float));
  float* lossb  = (float*)alloc(64 * sizeof(float));
  int*   bcnt   = (int*)alloc(512 * sizeof(int));       // grid-barrier counters
  // bf16 weight copies (~24.2 MB)
  bf16* w1if = (bf16*)alloc((size_t)G3 * FEATD * sizeof(bf16));
  bf16* w1ib = (bf16*)alloc((size_t)G3 * FEATD * sizeof(bf16));
  bf16* w1hf = (bf16*)alloc((size_t)G3 * HID * sizeof(bf16));
  bf16* w1hb = (bf16*)alloc((size_t)G3 * HID * sizeof(bf16));
  bf16* w2if = (bf16*)alloc((size_t)G3 * 2 * EMB * sizeof(bf16));
  bf16* w2ib = (bf16*)alloc((size_t)G3 * 2 * EMB * sizeof(bf16));
  bf16* w2hf = (bf16*)alloc((size_t)G3 * HID * sizeof(bf16));
  bf16* w2hb = (bf16*)alloc((size_t)G3 * HID * sizeof(bf16));
  bf16* wq   = (bf16*)alloc((size_t)EMB * EMB * sizeof(bf16));
  bf16* wo   = (bf16*)alloc((size_t)EMB * EMB * sizeof(bf16));
  (void)off; (void)ws_size; (void)in_sizes; (void)n_in; (void)out_size;

  bf16* xT = bufD;  // [T,B,FEAT] bf16, aliases bufD (dead before aoraw)

  const int M = (int)NTB;  // 16384
  dim3 blk(256);

  // 0. zero barrier counters (each launch -> replay-deterministic)
  hipMemsetAsync(bcnt, 0, 512 * sizeof(int), stream);

  // 0b. weight conversions fp32 -> bf16
  auto conv = [&](const float* s, bf16* d, size_t n) {
    f32_to_bf16<<<(int)((n / 4 + 255) / 256), blk, 0, stream>>>(s, d, (int)(n / 4));
  };
  conv(g1_wih_f, w1if, (size_t)G3 * FEATD);
  conv(g1_wih_b, w1ib, (size_t)G3 * FEATD);
  conv(g1_whh_f, w1hf, (size_t)G3 * HID);
  conv(g1_whh_b, w1hb, (size_t)G3 * HID);
  conv(g2_wih_f, w2if, (size_t)G3 * 2 * EMB);
  conv(g2_wih_b, w2ib, (size_t)G3 * 2 * EMB);
  conv(g2_whh_f, w2hf, (size_t)G3 * HID);
  conv(g2_whh_b, w2hb, (size_t)G3 * HID);
  conv(q_w, wq, (size_t)EMB * EMB);
  conv(out_w, wo, (size_t)EMB * EMB);

  // 1. features -> [T,B,FEAT] bf16
  transpose_feat<<<(BATCH * T_SEQ * FEATD + 255) / 256, blk, 0, stream>>>(features, xT);

  dim3 g_xp(G3 / 128, M / 128);   // (12,128)
  dim3 g_e(EMB / 128, M / 128);   // (8,128)

  // 2. GRU1 input projections
  gemm_mfma<<<g_xp, blk, 0, stream>>>(xT, FEATD, nullptr, 0, FEATD,
                                      w1if, FEATD, g1_bih_f, xpA, G3, M, G3, FEATD);
  gemm_mfma<<<g_xp, blk, 0, stream>>>(xT, FEATD, nullptr, 0, FEATD,
                                      w1ib, FEATD, g1_bih_b, xpB, G3, M, G3, FEATD);

  // 3. GRU1 recurrence -> enc (single persistent launch)
  gru_persist<<<GRU_NBLK, blk, 0, stream>>>(xpA, xpB, w1hf, w1hb,
                                            g1_bhh_f, g1_bhh_b, enc, bcnt);

  // 4. K/V (batch-independent) + Q projection -> bufE
  kv_kernel<<<4, blk, 0, stream>>>(ne_table, k_w, k_b, v_w, v_b, kkbuf, vvbuf);
  gemm_mfma<<<g_e, blk, 0, stream>>>(enc, EMB, nullptr, 0, EMB,
                                     wq, EMB, q_b, bufE, EMB, M, EMB, EMB);

  // 5. Attention (q=bufE -> aoraw=bufD) + output projection (-> aofin=bufE)
  attn_kernel<<<M * 2, blk, 0, stream>>>(bufE, kkbuf, vvbuf, bufD);
  gemm_mfma<<<g_e, blk, 0, stream>>>(bufD, EMB, nullptr, 0, EMB,
                                     wo, EMB, out_b, bufE, EMB, M, EMB, EMB);

  // 6. GRU2 input projections: dec_in = [enc, ao] via concat-A GEMM
  gemm_mfma<<<g_xp, blk, 0, stream>>>(enc, EMB, bufE, EMB, EMB,
                                      w2if, 2 * EMB, g2_bih_f, xpA, G3, M, G3, 2 * EMB);
  gemm_mfma<<<g_xp, blk, 0, stream>>>(enc, EMB, bufE, EMB, EMB,
                                      w2ib, 2 * EMB, g2_bih_b, xpB, G3, M, G3, 2 * EMB);

  // 7. GRU2 recurrence -> dec (bufD; aoraw dead)
  gru_persist<<<GRU_NBLK, blk, 0, stream>>>(xpA, xpB, w2hf, w2hb,
                                            g2_bhh_f, g2_bhh_b, bufD, bcnt + 256);

  // 8. Final linear + ne logits
  dec_logits_kernel<<<M / 4, blk, 0, stream>>>(bufD, lin_w, lin_b, ne_table, logits);

  // 9. CRF NLL + mean
  crf_kernel<<<BATCH, 64, 0, stream>>>(logits, labels, crf_start, crf_end, crf_trans, lossb);
  final_reduce<<<1, 64, 0, stream>>>(lossb, (float*)d_out);
}

// Round 6
// 5445.064 us; speedup vs baseline: 11.3801x; 1.4062x over previous
//
#include <hip/hip_runtime.h>
#include <hip/hip_bf16.h>
#include <math.h>

typedef __hip_bfloat16 bf16;
typedef __bf16 bf16x8 __attribute__((ext_vector_type(8)));
typedef float  f32x4  __attribute__((ext_vector_type(4)));
typedef unsigned long long u64;

#define T_SEQ 256
#define BATCH 64
#define FEATD 188
#define HID   512
#define EMB   1024
#define NTAG  14
#define G3    1536   // 3*HID
#define GRU_NBLK 32  // 16 blocks/dir x 32 hidden cols
#define DIR_NBLK 16  // barrier fan-in per direction

// ---------------------------------------------------------------------------
// fp32 -> bf16 weight conversion (vectorized x4; all n % 4 == 0)
// ---------------------------------------------------------------------------
__global__ __launch_bounds__(256) void f32_to_bf16(
    const float* __restrict__ src, bf16* __restrict__ dst, int n4)
{
  int i = blockIdx.x * 256 + threadIdx.x;
  if (i >= n4) return;
  float4 v = *(const float4*)(src + (size_t)i * 4);
  bf16 o[4] = {__float2bfloat16(v.x), __float2bfloat16(v.y),
               __float2bfloat16(v.z), __float2bfloat16(v.w)};
  *(ushort4*)(dst + (size_t)i * 4) = *(ushort4*)o;
}

// ---------------------------------------------------------------------------
// MFMA GEMM: C[M,N] = concat(A1,A2)[M,K] @ W[N,K]^T + bias. (validated R3)
// ---------------------------------------------------------------------------
__global__ __launch_bounds__(256) void gemm_mfma(
    const bf16* __restrict__ A1, int lda1,
    const bf16* __restrict__ A2, int lda2, int K1,
    const bf16* __restrict__ W, int ldw,
    const float* __restrict__ bias,
    bf16* __restrict__ C, int ldc,
    int M, int N, int K)
{
  __shared__ __bf16 As[128][40];
  __shared__ __bf16 Bs[128][40];
  const int bm = blockIdx.y * 128;
  const int bn = blockIdx.x * 128;
  const int tid = threadIdx.x;
  const int wave = tid >> 6, lane = tid & 63;
  const int wr = wave >> 1, wc = wave & 1;
  const int lr = lane & 15, lk = (lane >> 4) << 3;
  f32x4 acc[4][4] = {};
  for (int k0 = 0; k0 < K; k0 += 32) {
#pragma unroll
    for (int p = 0; p < 4; ++p) {
      int i = tid + p * 256;
      int row = i >> 3, q = i & 7;
      int kg = k0 + q * 4;
      ushort4 va{0, 0, 0, 0}, vb{0, 0, 0, 0};
      if (kg < K) {
        const bf16* srca = (kg < K1) ? A1 + (size_t)(bm + row) * lda1 + kg
                                     : A2 + (size_t)(bm + row) * lda2 + (kg - K1);
        va = *(const ushort4*)srca;
        vb = *(const ushort4*)(W + (size_t)(bn + row) * ldw + kg);
      }
      *(ushort4*)&As[row][q * 4] = va;
      *(ushort4*)&Bs[row][q * 4] = vb;
    }
    __syncthreads();
    bf16x8 af[4], bf_[4];
#pragma unroll
    for (int i = 0; i < 4; ++i)
      af[i] = *(const bf16x8*)&As[wr * 64 + i * 16 + lr][lk];
#pragma unroll
    for (int j = 0; j < 4; ++j)
      bf_[j] = *(const bf16x8*)&Bs[wc * 64 + j * 16 + lr][lk];
#pragma unroll
    for (int i = 0; i < 4; ++i)
#pragma unroll
      for (int j = 0; j < 4; ++j)
        acc[i][j] = __builtin_amdgcn_mfma_f32_16x16x32_bf16(af[i], bf_[j], acc[i][j], 0, 0, 0);
    __syncthreads();
  }
#pragma unroll
  for (int j = 0; j < 4; ++j) {
    int n = bn + wc * 64 + j * 16 + lr;
    float bv = bias ? bias[n] : 0.f;
#pragma unroll
    for (int i = 0; i < 4; ++i) {
#pragma unroll
      for (int p = 0; p < 4; ++p) {
        int m = bm + wr * 64 + i * 16 + (lane >> 4) * 4 + p;
        C[(size_t)m * ldc + n] = __float2bfloat16(acc[i][j][p] + bv);
      }
    }
  }
}

// ---------------------------------------------------------------------------
// features [B,T,FEAT] fp32 -> xT [T,B,FEAT] bf16
// ---------------------------------------------------------------------------
__global__ __launch_bounds__(256) void transpose_feat(
    const float* __restrict__ f, bf16* __restrict__ xT)
{
  const int idx = blockIdx.x * 256 + threadIdx.x;
  const int total = BATCH * T_SEQ * FEATD;
  if (idx >= total) return;
  const int i = idx % FEATD;
  const int r = idx / FEATD;
  const int b = r / T_SEQ;
  const int t = r % T_SEQ;
  xT[((size_t)t * BATCH + b) * FEATD + i] = __float2bfloat16(f[idx]);
}

// ---------------------------------------------------------------------------
// Persistent bidirectional GRU layer — fine-grained-coherence version.
// 32 blocks (dir x 16 col-tiles of 32 cols), 256 threads = 4 waves.
// Cross-block h exchange goes ONLY through relaxed agent-scope atomic
// u64 stores/loads (IF-coherent, no L2 writeback fences). Barrier:
// vmcnt drain -> syncthreads -> one relaxed fetch_add + relaxed spin.
// h_prev for the z-gate blend comes from an LDS double-buffer (same
// thread wrote it last step). Per-direction barrier counters.
// ---------------------------------------------------------------------------
__global__ __launch_bounds__(256) void gru_persist(
    const bf16* __restrict__ xp_f, const bf16* __restrict__ xp_b,
    const bf16* __restrict__ whh_f, const bf16* __restrict__ whh_b,
    const float* __restrict__ bhh_f, const float* __restrict__ bhh_b,
    bf16* __restrict__ out, int* __restrict__ cnt)
{
  const int blk = blockIdx.x;
  const int dir = blk >> 4;
  const int ct  = blk & 15;
  const bf16* xp   = dir ? xp_b  : xp_f;
  const bf16* whh  = dir ? whh_b : whh_f;
  const float* bhh = dir ? bhh_b : bhh_f;
  const int off = dir ? HID : 0;
  const int tid = threadIdx.x;
  const int wave = tid >> 6, lane = tid & 63;
  const int lr = lane & 15, lkq = lane >> 4;
  int* mycnt = cnt + dir * T_SEQ;

  // weights: rows r = g*32 + n, padded stride 520 (1040 B, 16B-aligned)
  __shared__ __bf16 Ws[96][520];
  __shared__ __bf16 Hst[2][64][36];   // h(t) staging, double-buffered
  for (int i = tid; i < 96 * 64; i += 256) {
    int r = i >> 6, q = i & 63;
    int grow = (r >> 5) * HID + ct * 32 + (r & 31);
    *(float4*)&Ws[r][q * 8] = *(const float4*)(whh + (size_t)grow * HID + q * 8);
  }
  __syncthreads();

  float bh[3][2];
#pragma unroll
  for (int g = 0; g < 3; ++g)
#pragma unroll
    for (int nf = 0; nf < 2; ++nf)
      bh[g][nf] = bhh[g * HID + ct * 32 + nf * 16 + lr];

  for (int s = 0; s < T_SEQ; ++s) {
    const int t = dir ? (T_SEQ - 1 - s) : s;
    const int cur = s & 1, prv = cur ^ 1;
    const size_t xbase = (size_t)t * BATCH * G3;

    // ---- xp prefetch (independent of h; HBM latency hides under h-loads)
    float xg[3][2][4];
#pragma unroll
    for (int p = 0; p < 4; ++p) {
      const int m = wave * 16 + lkq * 4 + p;
      const size_t xrow = xbase + (size_t)m * G3;
#pragma unroll
      for (int g = 0; g < 3; ++g)
#pragma unroll
        for (int nf = 0; nf < 2; ++nf)
          xg[g][nf][p] =
              __bfloat162float(xp[xrow + g * HID + ct * 32 + nf * 16 + lr]);
    }

    // ---- h_prev x W via MFMA; A-frags via IF-coherent atomic u64 loads
    f32x4 acc[3][2] = {};
    if (s > 0) {
      const bf16* arow = out + (size_t)(dir ? t + 1 : t - 1) * BATCH * EMB + off
                         + (size_t)(wave * 16 + lr) * EMB + lkq * 8;
#pragma unroll
      for (int ki = 0; ki < 16; ++ki) {
        union { u64 v[2]; bf16x8 f; } ua;
        ua.v[0] = __hip_atomic_load((const u64*)(arow + ki * 32),
                                    __ATOMIC_RELAXED, __HIP_MEMORY_SCOPE_AGENT);
        ua.v[1] = __hip_atomic_load((const u64*)(arow + ki * 32 + 4),
                                    __ATOMIC_RELAXED, __HIP_MEMORY_SCOPE_AGENT);
#pragma unroll
        for (int g = 0; g < 3; ++g)
#pragma unroll
          for (int nf = 0; nf < 2; ++nf) {
            bf16x8 b = *(const bf16x8*)&Ws[g * 32 + nf * 16 + lr][ki * 32 + lkq * 8];
            acc[g][nf] = __builtin_amdgcn_mfma_f32_16x16x32_bf16(ua.f, b, acc[g][nf], 0, 0, 0);
          }
      }
    }

    // ---- gates; h_prev blend element comes from own LDS double-buffer
#pragma unroll
    for (int nf = 0; nf < 2; ++nf) {
      const int cl = nf * 16 + lr;
#pragma unroll
      for (int p = 0; p < 4; ++p) {
        const int m = wave * 16 + lkq * 4 + p;
        float hp = (s > 0) ? (float)Hst[prv][m][cl] : 0.f;
        float r = 1.f / (1.f + expf(-(xg[0][nf][p] + acc[0][nf][p] + bh[0][nf])));
        float z = 1.f / (1.f + expf(-(xg[1][nf][p] + acc[1][nf][p] + bh[1][nf])));
        float n = tanhf(xg[2][nf][p] + r * (acc[2][nf][p] + bh[2][nf]));
        Hst[cur][m][cl] = (__bf16)((1.f - z) * n + z * hp);
      }
    }
    __syncthreads();   // Hst[cur] complete

    // ---- cooperative IF-coherent store of the 64x32 h tile (512 u64)
    const size_t obase = (size_t)t * BATCH * EMB + off + ct * 32;
    for (int i = tid; i < 512; i += 256) {
      int row = i >> 3, qq = i & 7;
      u64 v = *(const u64*)&Hst[cur][row][qq * 4];
      __hip_atomic_store((u64*)(out + obase + (size_t)row * EMB + qq * 4), v,
                         __ATOMIC_RELAXED, __HIP_MEMORY_SCOPE_AGENT);
    }
    asm volatile("s_waitcnt vmcnt(0)" ::: "memory");  // per-wave drain
    __syncthreads();                                  // all waves drained

    // ---- per-direction grid barrier (no cache-maintenance fences)
    if (tid == 0) {
      __hip_atomic_fetch_add(&mycnt[s], 1, __ATOMIC_RELAXED, __HIP_MEMORY_SCOPE_AGENT);
      while (__hip_atomic_load(&mycnt[s], __ATOMIC_RELAXED, __HIP_MEMORY_SCOPE_AGENT) < DIR_NBLK)
        __builtin_amdgcn_s_sleep(1);
    }
    __syncthreads();
  }
}

// ---------------------------------------------------------------------------
// K/V projections: ne batch-broadcast -> K/V collapse to [NT, EMB] fp32.
// ---------------------------------------------------------------------------
__global__ __launch_bounds__(256) void kv_kernel(
    const float* __restrict__ ne, const float* __restrict__ k_w,
    const float* __restrict__ k_b, const float* __restrict__ v_w,
    const float* __restrict__ v_b, float* __restrict__ kk,
    float* __restrict__ vv)
{
  const int e = blockIdx.x * 256 + threadIdx.x;
  if (e >= EMB) return;
#pragma unroll
  for (int s = 0; s < NTAG; ++s) {
    float a = k_b[e], c = v_b[e];
#pragma unroll
    for (int i = 0; i < NTAG; ++i) {
      float nv = ne[s * NTAG + i];
      a = fmaf(nv, k_w[e * NTAG + i], a);
      c = fmaf(nv, v_w[e * NTAG + i], c);
    }
    kk[s * EMB + e] = a;
    vv[s * EMB + e] = c;
  }
}

// ---------------------------------------------------------------------------
// Attention: 4 (tb,head) units per 256-thread block. S=14 keys, HD=128.
// ---------------------------------------------------------------------------
__global__ __launch_bounds__(256) void attn_kernel(
    const bf16* __restrict__ q, const float* __restrict__ kk,
    const float* __restrict__ vv, bf16* __restrict__ ao)
{
  const int unit = blockIdx.x * 4 + (threadIdx.x >> 6);
  const int h = unit & 7;
  const int tb = unit >> 3;
  const int lane = threadIdx.x & 63;
  const size_t qbase = (size_t)tb * EMB + h * 128;
  const int kbase = h * 128 + lane;
  float q0 = __bfloat162float(q[qbase + lane]);
  float q1 = __bfloat162float(q[qbase + 64 + lane]);
  float sc[NTAG];
#pragma unroll
  for (int j = 0; j < NTAG; ++j) {
    float p = q0 * kk[j * EMB + kbase] + q1 * kk[j * EMB + 64 + kbase];
#pragma unroll
    for (int d = 32; d; d >>= 1) p += __shfl_xor(p, d);
    sc[j] = p * 0.088388347648318447f;  // 1/sqrt(128)
  }
  float m = sc[0];
#pragma unroll
  for (int j = 1; j < NTAG; ++j) m = fmaxf(m, sc[j]);
  float sum = 0.f;
#pragma unroll
  for (int j = 0; j < NTAG; ++j) { sc[j] = expf(sc[j] - m); sum += sc[j]; }
  float inv = 1.f / sum;
  float o0 = 0.f, o1 = 0.f;
#pragma unroll
  for (int j = 0; j < NTAG; ++j) {
    float p = sc[j] * inv;
    o0 = fmaf(p, vv[j * EMB + kbase], o0);
    o1 = fmaf(p, vv[j * EMB + 64 + kbase], o1);
  }
  ao[qbase + lane] = __float2bfloat16(o0);
  ao[qbase + 64 + lane] = __float2bfloat16(o1);
}

// ---------------------------------------------------------------------------
// Fused final linear + ne-table logits: 4 (t,b) units per block.
// ---------------------------------------------------------------------------
__global__ __launch_bounds__(256) void dec_logits_kernel(
    const bf16* __restrict__ dec, const float* __restrict__ lin_w,
    const float* __restrict__ lin_b, const float* __restrict__ ne,
    float* __restrict__ logits)
{
  const int tb = blockIdx.x * 4 + (threadIdx.x >> 6);
  const int t = tb >> 6;
  const int b = tb & 63;
  const int lane = threadIdx.x & 63;
  const bf16* drow = dec + (size_t)tb * EMB;
  float dv[16];
#pragma unroll
  for (int i = 0; i < 16; ++i) dv[i] = __bfloat162float(drow[lane + 64 * i]);
  float dl[NTAG];
#pragma unroll
  for (int n = 0; n < NTAG; ++n) {
    float p = 0.f;
#pragma unroll
    for (int i = 0; i < 16; ++i)
      p = fmaf(dv[i], lin_w[n * EMB + lane + 64 * i], p);
#pragma unroll
    for (int d = 32; d; d >>= 1) p += __shfl_xor(p, d);
    dl[n] = p + lin_b[n];
  }
  if (lane < NTAG) {
    float acc = 0.f;
#pragma unroll
    for (int d2 = 0; d2 < NTAG; ++d2)
      acc = fmaf(dl[d2], ne[lane * NTAG + d2], acc);
    logits[((size_t)b * T_SEQ + t) * NTAG + lane] = acc * 0.26726124191242439f; // 1/sqrt(14)
  }
}

// ---------------------------------------------------------------------------
// CRF NLL per batch element (one wave per b; alpha recurrence over T).
// ---------------------------------------------------------------------------
__global__ __launch_bounds__(64) void crf_kernel(
    const float* __restrict__ logits, const int* __restrict__ labels,
    const float* __restrict__ cstart, const float* __restrict__ cend,
    const float* __restrict__ ctrans, float* __restrict__ lossb)
{
  const int b = blockIdx.x;
  const int lane = threadIdx.x;
  __shared__ float al[NTAG];
  __shared__ float tr[NTAG * NTAG];
  __shared__ float tmp[NTAG];
  const float* lg = logits + (size_t)b * T_SEQ * NTAG;
  const int* lab = labels + (size_t)b * T_SEQ;
  for (int i = lane; i < NTAG * NTAG; i += 64) tr[i] = ctrans[i];
  if (lane < NTAG) al[lane] = cstart[lane] + lg[lane];
  __syncthreads();
  for (int t = 1; t < T_SEQ; ++t) {
    float v = 0.f;
    if (lane < NTAG) {
      float mx = -1e30f;
#pragma unroll
      for (int i = 0; i < NTAG; ++i) mx = fmaxf(mx, al[i] + tr[i * NTAG + lane]);
      float sm = 0.f;
#pragma unroll
      for (int i = 0; i < NTAG; ++i) sm += expf(al[i] + tr[i * NTAG + lane] - mx);
      v = mx + logf(sm) + lg[t * NTAG + lane];
    }
    __syncthreads();
    if (lane < NTAG) al[lane] = v;
    __syncthreads();
  }
  float em = 0.f;
  for (int t = lane; t < T_SEQ; t += 64) em += lg[t * NTAG + lab[t]];
  float trs = 0.f;
  for (int t = lane; t < T_SEQ - 1; t += 64) trs += tr[lab[t] * NTAG + lab[t + 1]];
  float p = em + trs;
#pragma unroll
  for (int d = 32; d; d >>= 1) p += __shfl_xor(p, d);
  if (lane < NTAG) tmp[lane] = al[lane] + cend[lane];
  __syncthreads();
  if (lane == 0) {
    float num = p + cstart[lab[0]] + cend[lab[T_SEQ - 1]];
    float mx = tmp[0];
#pragma unroll
    for (int i = 1; i < NTAG; ++i) mx = fmaxf(mx, tmp[i]);
    float sm = 0.f;
#pragma unroll
    for (int i = 0; i < NTAG; ++i) sm += expf(tmp[i] - mx);
    float den = mx + logf(sm);
    lossb[b] = -(num - den);
  }
}

__global__ __launch_bounds__(64) void final_reduce(
    const float* __restrict__ lossb, float* __restrict__ out)
{
  float v = lossb[threadIdx.x];
#pragma unroll
  for (int d = 32; d; d >>= 1) v += __shfl_xor(v, d);
  if (threadIdx.x == 0) out[0] = v * (1.f / 64.f);
}

// ---------------------------------------------------------------------------
extern "C" void kernel_launch(void* const* d_in, const int* in_sizes, int n_in,
                              void* d_out, int out_size, void* d_ws, size_t ws_size,
                              hipStream_t stream)
{
  const float* features = (const float*)d_in[0];
  const int*   labels   = (const int*)d_in[1];
  const float* ne_table = (const float*)d_in[2];
  const float* g1_wih_f = (const float*)d_in[3];
  const float* g1_whh_f = (const float*)d_in[4];
  const float* g1_bih_f = (const float*)d_in[5];
  const float* g1_bhh_f = (const float*)d_in[6];
  const float* g1_wih_b = (const float*)d_in[7];
  const float* g1_whh_b = (const float*)d_in[8];
  const float* g1_bih_b = (const float*)d_in[9];
  const float* g1_bhh_b = (const float*)d_in[10];
  const float* g2_wih_f = (const float*)d_in[11];
  const float* g2_whh_f = (const float*)d_in[12];
  const float* g2_bih_f = (const float*)d_in[13];
  const float* g2_bhh_f = (const float*)d_in[14];
  const float* g2_wih_b = (const float*)d_in[15];
  const float* g2_whh_b = (const float*)d_in[16];
  const float* g2_bih_b = (const float*)d_in[17];
  const float* g2_bhh_b = (const float*)d_in[18];
  const float* q_w   = (const float*)d_in[19];
  const float* q_b   = (const float*)d_in[20];
  const float* k_w   = (const float*)d_in[21];
  const float* k_b   = (const float*)d_in[22];
  const float* v_w   = (const float*)d_in[23];
  const float* v_b   = (const float*)d_in[24];
  const float* out_w = (const float*)d_in[25];
  const float* out_b = (const float*)d_in[26];
  const float* lin_w = (const float*)d_in[27];
  const float* lin_b = (const float*)d_in[28];
  const float* crf_start = (const float*)d_in[29];
  const float* crf_end   = (const float*)d_in[30];
  const float* crf_trans = (const float*)d_in[31];

  // ---- workspace layout (~218 MB) ----
  const size_t NTB = (size_t)T_SEQ * BATCH;      // 16384
  char* base = (char*)d_ws;
  size_t off = 0;
  auto alloc = [&](size_t bytes) {
    char* p = base + off;
    off += (bytes + 255) & ~(size_t)255;
    return p;
  };
  bf16* xpA  = (bf16*)alloc(NTB * G3 * sizeof(bf16));   // xp fwd (gru1, then gru2)
  bf16* xpB  = (bf16*)alloc(NTB * G3 * sizeof(bf16));   // xp bwd
  bf16* enc  = (bf16*)alloc(NTB * EMB * sizeof(bf16));  // gru1 output
  bf16* bufD = (bf16*)alloc(NTB * EMB * sizeof(bf16));  // xT -> aoraw -> dec
  bf16* bufE = (bf16*)alloc(NTB * EMB * sizeof(bf16));  // q -> aofin
  float* kkbuf  = (float*)alloc((size_t)NTAG * EMB * sizeof(float));
  float* vvbuf  = (float*)alloc((size_t)NTAG * EMB * sizeof(float));
  float* logits = (float*)alloc(NTB * NTAG * sizeof(float));
  float* lossb  = (float*)alloc(64 * sizeof(float));
  int*   bcnt   = (int*)alloc(1024 * sizeof(int));      // barrier counters (2 layers x 2 dirs x 256)
  // bf16 weight copies (~24.2 MB)
  bf16* w1if = (bf16*)alloc((size_t)G3 * FEATD * sizeof(bf16));
  bf16* w1ib = (bf16*)alloc((size_t)G3 * FEATD * sizeof(bf16));
  bf16* w1hf = (bf16*)alloc((size_t)G3 * HID * sizeof(bf16));
  bf16* w1hb = (bf16*)alloc((size_t)G3 * HID * sizeof(bf16));
  bf16* w2if = (bf16*)alloc((size_t)G3 * 2 * EMB * sizeof(bf16));
  bf16* w2ib = (bf16*)alloc((size_t)G3 * 2 * EMB * sizeof(bf16));
  bf16* w2hf = (bf16*)alloc((size_t)G3 * HID * sizeof(bf16));
  bf16* w2hb = (bf16*)alloc((size_t)G3 * HID * sizeof(bf16));
  bf16* wq   = (bf16*)alloc((size_t)EMB * EMB * sizeof(bf16));
  bf16* wo   = (bf16*)alloc((size_t)EMB * EMB * sizeof(bf16));
  (void)off; (void)ws_size; (void)in_sizes; (void)n_in; (void)out_size;

  bf16* xT = bufD;  // [T,B,FEAT] bf16, aliases bufD (dead before aoraw)

  const int M = (int)NTB;  // 16384
  dim3 blk(256);

  // 0. zero barrier counters (each launch -> replay-deterministic)
  hipMemsetAsync(bcnt, 0, 1024 * sizeof(int), stream);

  // 0b. weight conversions fp32 -> bf16
  auto conv = [&](const float* s, bf16* d, size_t n) {
    f32_to_bf16<<<(int)((n / 4 + 255) / 256), blk, 0, stream>>>(s, d, (int)(n / 4));
  };
  conv(g1_wih_f, w1if, (size_t)G3 * FEATD);
  conv(g1_wih_b, w1ib, (size_t)G3 * FEATD);
  conv(g1_whh_f, w1hf, (size_t)G3 * HID);
  conv(g1_whh_b, w1hb, (size_t)G3 * HID);
  conv(g2_wih_f, w2if, (size_t)G3 * 2 * EMB);
  conv(g2_wih_b, w2ib, (size_t)G3 * 2 * EMB);
  conv(g2_whh_f, w2hf, (size_t)G3 * HID);
  conv(g2_whh_b, w2hb, (size_t)G3 * HID);
  conv(q_w, wq, (size_t)EMB * EMB);
  conv(out_w, wo, (size_t)EMB * EMB);

  // 1. features -> [T,B,FEAT] bf16
  transpose_feat<<<(BATCH * T_SEQ * FEATD + 255) / 256, blk, 0, stream>>>(features, xT);

  dim3 g_xp(G3 / 128, M / 128);   // (12,128)
  dim3 g_e(EMB / 128, M / 128);   // (8,128)

  // 2. GRU1 input projections
  gemm_mfma<<<g_xp, blk, 0, stream>>>(xT, FEATD, nullptr, 0, FEATD,
                                      w1if, FEATD, g1_bih_f, xpA, G3, M, G3, FEATD);
  gemm_mfma<<<g_xp, blk, 0, stream>>>(xT, FEATD, nullptr, 0, FEATD,
                                      w1ib, FEATD, g1_bih_b, xpB, G3, M, G3, FEATD);

  // 3. GRU1 recurrence -> enc (single persistent launch)
  gru_persist<<<GRU_NBLK, blk, 0, stream>>>(xpA, xpB, w1hf, w1hb,
                                            g1_bhh_f, g1_bhh_b, enc, bcnt);

  // 4. K/V (batch-independent) + Q projection -> bufE
  kv_kernel<<<4, blk, 0, stream>>>(ne_table, k_w, k_b, v_w, v_b, kkbuf, vvbuf);
  gemm_mfma<<<g_e, blk, 0, stream>>>(enc, EMB, nullptr, 0, EMB,
                                     wq, EMB, q_b, bufE, EMB, M, EMB, EMB);

  // 5. Attention (q=bufE -> aoraw=bufD) + output projection (-> aofin=bufE)
  attn_kernel<<<M * 2, blk, 0, stream>>>(bufE, kkbuf, vvbuf, bufD);
  gemm_mfma<<<g_e, blk, 0, stream>>>(bufD, EMB, nullptr, 0, EMB,
                                     wo, EMB, out_b, bufE, EMB, M, EMB, EMB);

  // 6. GRU2 input projections: dec_in = [enc, ao] via concat-A GEMM
  gemm_mfma<<<g_xp, blk, 0, stream>>>(enc, EMB, bufE, EMB, EMB,
                                      w2if, 2 * EMB, g2_bih_f, xpA, G3, M, G3, 2 * EMB);
  gemm_mfma<<<g_xp, blk, 0, stream>>>(enc, EMB, bufE, EMB, EMB,
                                      w2ib, 2 * EMB, g2_bih_b, xpB, G3, M, G3, 2 * EMB);

  // 7. GRU2 recurrence -> dec (bufD; aoraw dead)
  gru_persist<<<GRU_NBLK, blk, 0, stream>>>(xpA, xpB, w2hf, w2hb,
                                            g2_bhh_f, g2_bhh_b, bufD, bcnt + 512);

  // 8. Final linear + ne logits
  dec_logits_kernel<<<M / 4, blk, 0, stream>>>(bufD, lin_w, lin_b, ne_table, logits);

  // 9. CRF NLL + mean
  crf_kernel<<<BATCH, 64, 0, stream>>>(logits, labels, crf_start, crf_end, crf_trans, lossb);
  final_reduce<<<1, 64, 0, stream>>>(lossb, (float*)d_out);
}

// Round 7
// 5042.097 us; speedup vs baseline: 12.2896x; 1.0799x over previous
//
#include <hip/hip_runtime.h>
#include <hip/hip_bf16.h>
#include <math.h>

typedef __hip_bfloat16 bf16;
typedef __bf16 bf16x8 __attribute__((ext_vector_type(8)));
typedef float  f32x4  __attribute__((ext_vector_type(4)));
typedef unsigned long long u64;

#define T_SEQ 256
#define BATCH 64
#define FEATD 188
#define HID   512
#define EMB   1024
#define NTAG  14
#define G3    1536   // 3*HID
#define GRU_NBLK 32  // 16 blocks/dir x 32 hidden cols
#define DIR_NBLK 16  // barrier fan-in per direction

// ---------------------------------------------------------------------------
// fp32 -> bf16 weight conversion (vectorized x4; all n % 4 == 0)
// ---------------------------------------------------------------------------
__global__ __launch_bounds__(256) void f32_to_bf16(
    const float* __restrict__ src, bf16* __restrict__ dst, int n4)
{
  int i = blockIdx.x * 256 + threadIdx.x;
  if (i >= n4) return;
  float4 v = *(const float4*)(src + (size_t)i * 4);
  bf16 o[4] = {__float2bfloat16(v.x), __float2bfloat16(v.y),
               __float2bfloat16(v.z), __float2bfloat16(v.w)};
  *(ushort4*)(dst + (size_t)i * 4) = *(ushort4*)o;
}

// ---------------------------------------------------------------------------
// MFMA GEMM: C[M,N] = concat(A1,A2)[M,K] @ W[N,K]^T + bias. (validated R3)
// ---------------------------------------------------------------------------
__global__ __launch_bounds__(256) void gemm_mfma(
    const bf16* __restrict__ A1, int lda1,
    const bf16* __restrict__ A2, int lda2, int K1,
    const bf16* __restrict__ W, int ldw,
    const float* __restrict__ bias,
    bf16* __restrict__ C, int ldc,
    int M, int N, int K)
{
  __shared__ __bf16 As[128][40];
  __shared__ __bf16 Bs[128][40];
  const int bm = blockIdx.y * 128;
  const int bn = blockIdx.x * 128;
  const int tid = threadIdx.x;
  const int wave = tid >> 6, lane = tid & 63;
  const int wr = wave >> 1, wc = wave & 1;
  const int lr = lane & 15, lk = (lane >> 4) << 3;
  f32x4 acc[4][4] = {};
  for (int k0 = 0; k0 < K; k0 += 32) {
#pragma unroll
    for (int p = 0; p < 4; ++p) {
      int i = tid + p * 256;
      int row = i >> 3, q = i & 7;
      int kg = k0 + q * 4;
      ushort4 va{0, 0, 0, 0}, vb{0, 0, 0, 0};
      if (kg < K) {
        const bf16* srca = (kg < K1) ? A1 + (size_t)(bm + row) * lda1 + kg
                                     : A2 + (size_t)(bm + row) * lda2 + (kg - K1);
        va = *(const ushort4*)srca;
        vb = *(const ushort4*)(W + (size_t)(bn + row) * ldw + kg);
      }
      *(ushort4*)&As[row][q * 4] = va;
      *(ushort4*)&Bs[row][q * 4] = vb;
    }
    __syncthreads();
    bf16x8 af[4], bf_[4];
#pragma unroll
    for (int i = 0; i < 4; ++i)
      af[i] = *(const bf16x8*)&As[wr * 64 + i * 16 + lr][lk];
#pragma unroll
    for (int j = 0; j < 4; ++j)
      bf_[j] = *(const bf16x8*)&Bs[wc * 64 + j * 16 + lr][lk];
#pragma unroll
    for (int i = 0; i < 4; ++i)
#pragma unroll
      for (int j = 0; j < 4; ++j)
        acc[i][j] = __builtin_amdgcn_mfma_f32_16x16x32_bf16(af[i], bf_[j], acc[i][j], 0, 0, 0);
    __syncthreads();
  }
#pragma unroll
  for (int j = 0; j < 4; ++j) {
    int n = bn + wc * 64 + j * 16 + lr;
    float bv = bias ? bias[n] : 0.f;
#pragma unroll
    for (int i = 0; i < 4; ++i) {
#pragma unroll
      for (int p = 0; p < 4; ++p) {
        int m = bm + wr * 64 + i * 16 + (lane >> 4) * 4 + p;
        C[(size_t)m * ldc + n] = __float2bfloat16(acc[i][j][p] + bv);
      }
    }
  }
}

// ---------------------------------------------------------------------------
// features [B,T,FEAT] fp32 -> xT [T,B,FEAT] bf16
// ---------------------------------------------------------------------------
__global__ __launch_bounds__(256) void transpose_feat(
    const float* __restrict__ f, bf16* __restrict__ xT)
{
  const int idx = blockIdx.x * 256 + threadIdx.x;
  const int total = BATCH * T_SEQ * FEATD;
  if (idx >= total) return;
  const int i = idx % FEATD;
  const int r = idx / FEATD;
  const int b = r / T_SEQ;
  const int t = r % T_SEQ;
  xT[((size_t)t * BATCH + b) * FEATD + i] = __float2bfloat16(f[idx]);
}

// ---------------------------------------------------------------------------
// Persistent bidirectional GRU layer — pipelined fine-grained-coherence.
// 32 blocks (dir x 16 col-tiles of 32 cols), 256 threads = 4 waves,
// __launch_bounds__(256,1) -> full VGPR budget so all 32 h-loads fly at once.
// Per step: batched IF-coherent h loads -> MFMA -> gates -> LDS stage ->
// coherent stores -> drain -> ARRIVE -> prefetch next xp (hides under wait)
// -> spin-wait -> next step. No cache-maintenance fences anywhere.
// ---------------------------------------------------------------------------
__global__ __launch_bounds__(256, 1) void gru_persist(
    const bf16* __restrict__ xp_f, const bf16* __restrict__ xp_b,
    const bf16* __restrict__ whh_f, const bf16* __restrict__ whh_b,
    const float* __restrict__ bhh_f, const float* __restrict__ bhh_b,
    bf16* __restrict__ out, int* __restrict__ cnt)
{
  const int blk = blockIdx.x;
  const int dir = blk >> 4;
  const int ct  = blk & 15;
  const bf16* xp   = dir ? xp_b  : xp_f;
  const bf16* whh  = dir ? whh_b : whh_f;
  const float* bhh = dir ? bhh_b : bhh_f;
  const int off = dir ? HID : 0;
  const int tid = threadIdx.x;
  const int wave = tid >> 6, lane = tid & 63;
  const int lr = lane & 15, lkq = lane >> 4;
  int* mycnt = cnt + dir * T_SEQ;

  // weights: rows r = g*32 + n, padded stride 520 (1040 B, 16B-aligned)
  __shared__ __bf16 Ws[96][520];
  __shared__ __bf16 Hst[2][64][36];   // h(t) staging, double-buffered
  for (int i = tid; i < 96 * 64; i += 256) {
    int r = i >> 6, q = i & 63;
    int grow = (r >> 5) * HID + ct * 32 + (r & 31);
    *(float4*)&Ws[r][q * 8] = *(const float4*)(whh + (size_t)grow * HID + q * 8);
  }
  __syncthreads();

  float bh[3][2];
#pragma unroll
  for (int g = 0; g < 3; ++g)
#pragma unroll
    for (int nf = 0; nf < 2; ++nf)
      bh[g][nf] = bhh[g * HID + ct * 32 + nf * 16 + lr];

  // xp held in bf16 regs; converted at use. Prologue: prefetch step 0.
  bf16 xc[3][2][4];
  {
    const int t0 = dir ? (T_SEQ - 1) : 0;
    const size_t xbase = (size_t)t0 * BATCH * G3;
#pragma unroll
    for (int p = 0; p < 4; ++p) {
      const size_t xrow = xbase + (size_t)(wave * 16 + lkq * 4 + p) * G3;
#pragma unroll
      for (int g = 0; g < 3; ++g)
#pragma unroll
        for (int nf = 0; nf < 2; ++nf)
          xc[g][nf][p] = xp[xrow + g * HID + ct * 32 + nf * 16 + lr];
    }
  }

  for (int s = 0; s < T_SEQ; ++s) {
    const int t = dir ? (T_SEQ - 1 - s) : s;
    const int cur = s & 1, prv = cur ^ 1;

    // ---- batched IF-coherent h prefetch (32 u64 in flight), then MFMA
    f32x4 acc[3][2] = {};
    if (s > 0) {
      const bf16* arow = out + (size_t)(dir ? t + 1 : t - 1) * BATCH * EMB + off
                         + (size_t)(wave * 16 + lr) * EMB + lkq * 8;
      union { u64 v[2]; bf16x8 f; } hb[16];
#pragma unroll
      for (int ki = 0; ki < 16; ++ki) {
        hb[ki].v[0] = __hip_atomic_load((const u64*)(arow + ki * 32),
                                        __ATOMIC_RELAXED, __HIP_MEMORY_SCOPE_AGENT);
        hb[ki].v[1] = __hip_atomic_load((const u64*)(arow + ki * 32 + 4),
                                        __ATOMIC_RELAXED, __HIP_MEMORY_SCOPE_AGENT);
      }
#pragma unroll
      for (int ki = 0; ki < 16; ++ki) {
#pragma unroll
        for (int g = 0; g < 3; ++g)
#pragma unroll
          for (int nf = 0; nf < 2; ++nf) {
            bf16x8 b = *(const bf16x8*)&Ws[g * 32 + nf * 16 + lr][ki * 32 + lkq * 8];
            acc[g][nf] = __builtin_amdgcn_mfma_f32_16x16x32_bf16(hb[ki].f, b, acc[g][nf], 0, 0, 0);
          }
      }
    }

    // ---- gates; h_prev blend element from own LDS double-buffer
#pragma unroll
    for (int nf = 0; nf < 2; ++nf) {
      const int cl = nf * 16 + lr;
#pragma unroll
      for (int p = 0; p < 4; ++p) {
        const int m = wave * 16 + lkq * 4 + p;
        float hp = (s > 0) ? (float)Hst[prv][m][cl] : 0.f;
        float xr = __bfloat162float(xc[0][nf][p]);
        float xz = __bfloat162float(xc[1][nf][p]);
        float xn = __bfloat162float(xc[2][nf][p]);
        float r = 1.f / (1.f + expf(-(xr + acc[0][nf][p] + bh[0][nf])));
        float z = 1.f / (1.f + expf(-(xz + acc[1][nf][p] + bh[1][nf])));
        float n = tanhf(xn + r * (acc[2][nf][p] + bh[2][nf]));
        Hst[cur][m][cl] = (__bf16)((1.f - z) * n + z * hp);
      }
    }
    __syncthreads();   // Hst[cur] complete

    // ---- cooperative IF-coherent store of the 64x32 h tile (512 u64)
    const size_t obase = (size_t)t * BATCH * EMB + off + ct * 32;
    for (int i = tid; i < 512; i += 256) {
      int row = i >> 3, qq = i & 7;
      u64 v = *(const u64*)&Hst[cur][row][qq * 4];
      __hip_atomic_store((u64*)(out + obase + (size_t)row * EMB + qq * 4), v,
                         __ATOMIC_RELAXED, __HIP_MEMORY_SCOPE_AGENT);
    }
    asm volatile("s_waitcnt vmcnt(0)" ::: "memory");  // per-wave drain
    __syncthreads();                                  // all waves drained

    // ---- ARRIVE early
    if (tid == 0)
      __hip_atomic_fetch_add(&mycnt[s], 1, __ATOMIC_RELAXED, __HIP_MEMORY_SCOPE_AGENT);

    // ---- prefetch next step's xp while waiting (HBM latency hidden)
    if (s + 1 < T_SEQ) {
      const int tn = dir ? (T_SEQ - 2 - s) : (s + 1);
      const size_t xb2 = (size_t)tn * BATCH * G3;
#pragma unroll
      for (int p = 0; p < 4; ++p) {
        const size_t xrow = xb2 + (size_t)(wave * 16 + lkq * 4 + p) * G3;
#pragma unroll
        for (int g = 0; g < 3; ++g)
#pragma unroll
          for (int nf = 0; nf < 2; ++nf)
            xc[g][nf][p] = xp[xrow + g * HID + ct * 32 + nf * 16 + lr];
      }
    }

    // ---- WAIT
    if (tid == 0) {
      while (__hip_atomic_load(&mycnt[s], __ATOMIC_RELAXED, __HIP_MEMORY_SCOPE_AGENT) < DIR_NBLK)
        __builtin_amdgcn_s_sleep(1);
    }
    __syncthreads();
  }
}

// ---------------------------------------------------------------------------
// K/V projections: ne batch-broadcast -> K/V collapse to [NT, EMB] fp32.
// ---------------------------------------------------------------------------
__global__ __launch_bounds__(256) void kv_kernel(
    const float* __restrict__ ne, const float* __restrict__ k_w,
    const float* __restrict__ k_b, const float* __restrict__ v_w,
    const float* __restrict__ v_b, float* __restrict__ kk,
    float* __restrict__ vv)
{
  const int e = blockIdx.x * 256 + threadIdx.x;
  if (e >= EMB) return;
#pragma unroll
  for (int s = 0; s < NTAG; ++s) {
    float a = k_b[e], c = v_b[e];
#pragma unroll
    for (int i = 0; i < NTAG; ++i) {
      float nv = ne[s * NTAG + i];
      a = fmaf(nv, k_w[e * NTAG + i], a);
      c = fmaf(nv, v_w[e * NTAG + i], c);
    }
    kk[s * EMB + e] = a;
    vv[s * EMB + e] = c;
  }
}

// ---------------------------------------------------------------------------
// Attention: 4 (tb,head) units per 256-thread block. S=14 keys, HD=128.
// ---------------------------------------------------------------------------
__global__ __launch_bounds__(256) void attn_kernel(
    const bf16* __restrict__ q, const float* __restrict__ kk,
    const float* __restrict__ vv, bf16* __restrict__ ao)
{
  const int unit = blockIdx.x * 4 + (threadIdx.x >> 6);
  const int h = unit & 7;
  const int tb = unit >> 3;
  const int lane = threadIdx.x & 63;
  const size_t qbase = (size_t)tb * EMB + h * 128;
  const int kbase = h * 128 + lane;
  float q0 = __bfloat162float(q[qbase + lane]);
  float q1 = __bfloat162float(q[qbase + 64 + lane]);
  float sc[NTAG];
#pragma unroll
  for (int j = 0; j < NTAG; ++j) {
    float p = q0 * kk[j * EMB + kbase] + q1 * kk[j * EMB + 64 + kbase];
#pragma unroll
    for (int d = 32; d; d >>= 1) p += __shfl_xor(p, d);
    sc[j] = p * 0.088388347648318447f;  // 1/sqrt(128)
  }
  float m = sc[0];
#pragma unroll
  for (int j = 1; j < NTAG; ++j) m = fmaxf(m, sc[j]);
  float sum = 0.f;
#pragma unroll
  for (int j = 0; j < NTAG; ++j) { sc[j] = expf(sc[j] - m); sum += sc[j]; }
  float inv = 1.f / sum;
  float o0 = 0.f, o1 = 0.f;
#pragma unroll
  for (int j = 0; j < NTAG; ++j) {
    float p = sc[j] * inv;
    o0 = fmaf(p, vv[j * EMB + kbase], o0);
    o1 = fmaf(p, vv[j * EMB + 64 + kbase], o1);
  }
  ao[qbase + lane] = __float2bfloat16(o0);
  ao[qbase + 64 + lane] = __float2bfloat16(o1);
}

// ---------------------------------------------------------------------------
// Fused final linear + ne-table logits: 4 (t,b) units per block.
// ---------------------------------------------------------------------------
__global__ __launch_bounds__(256) void dec_logits_kernel(
    const bf16* __restrict__ dec, const float* __restrict__ lin_w,
    const float* __restrict__ lin_b, const float* __restrict__ ne,
    float* __restrict__ logits)
{
  const int tb = blockIdx.x * 4 + (threadIdx.x >> 6);
  const int t = tb >> 6;
  const int b = tb & 63;
  const int lane = threadIdx.x & 63;
  const bf16* drow = dec + (size_t)tb * EMB;
  float dv[16];
#pragma unroll
  for (int i = 0; i < 16; ++i) dv[i] = __bfloat162float(drow[lane + 64 * i]);
  float dl[NTAG];
#pragma unroll
  for (int n = 0; n < NTAG; ++n) {
    float p = 0.f;
#pragma unroll
    for (int i = 0; i < 16; ++i)
      p = fmaf(dv[i], lin_w[n * EMB + lane + 64 * i], p);
#pragma unroll
    for (int d = 32; d; d >>= 1) p += __shfl_xor(p, d);
    dl[n] = p + lin_b[n];
  }
  if (lane < NTAG) {
    float acc = 0.f;
#pragma unroll
    for (int d2 = 0; d2 < NTAG; ++d2)
      acc = fmaf(dl[d2], ne[lane * NTAG + d2], acc);
    logits[((size_t)b * T_SEQ + t) * NTAG + lane] = acc * 0.26726124191242439f; // 1/sqrt(14)
  }
}

// ---------------------------------------------------------------------------
// CRF NLL per batch element (one wave per b; alpha recurrence over T).
// ---------------------------------------------------------------------------
__global__ __launch_bounds__(64) void crf_kernel(
    const float* __restrict__ logits, const int* __restrict__ labels,
    const float* __restrict__ cstart, const float* __restrict__ cend,
    const float* __restrict__ ctrans, float* __restrict__ lossb)
{
  const int b = blockIdx.x;
  const int lane = threadIdx.x;
  __shared__ float al[NTAG];
  __shared__ float tr[NTAG * NTAG];
  __shared__ float tmp[NTAG];
  const float* lg = logits + (size_t)b * T_SEQ * NTAG;
  const int* lab = labels + (size_t)b * T_SEQ;
  for (int i = lane; i < NTAG * NTAG; i += 64) tr[i] = ctrans[i];
  if (lane < NTAG) al[lane] = cstart[lane] + lg[lane];
  __syncthreads();
  for (int t = 1; t < T_SEQ; ++t) {
    float v = 0.f;
    if (lane < NTAG) {
      float mx = -1e30f;
#pragma unroll
      for (int i = 0; i < NTAG; ++i) mx = fmaxf(mx, al[i] + tr[i * NTAG + lane]);
      float sm = 0.f;
#pragma unroll
      for (int i = 0; i < NTAG; ++i) sm += expf(al[i] + tr[i * NTAG + lane] - mx);
      v = mx + logf(sm) + lg[t * NTAG + lane];
    }
    __syncthreads();
    if (lane < NTAG) al[lane] = v;
    __syncthreads();
  }
  float em = 0.f;
  for (int t = lane; t < T_SEQ; t += 64) em += lg[t * NTAG + lab[t]];
  float trs = 0.f;
  for (int t = lane; t < T_SEQ - 1; t += 64) trs += tr[lab[t] * NTAG + lab[t + 1]];
  float p = em + trs;
#pragma unroll
  for (int d = 32; d; d >>= 1) p += __shfl_xor(p, d);
  if (lane < NTAG) tmp[lane] = al[lane] + cend[lane];
  __syncthreads();
  if (lane == 0) {
    float num = p + cstart[lab[0]] + cend[lab[T_SEQ - 1]];
    float mx = tmp[0];
#pragma unroll
    for (int i = 1; i < NTAG; ++i) mx = fmaxf(mx, tmp[i]);
    float sm = 0.f;
#pragma unroll
    for (int i = 0; i < NTAG; ++i) sm += expf(tmp[i] - mx);
    float den = mx + logf(sm);
    lossb[b] = -(num - den);
  }
}

__global__ __launch_bounds__(64) void final_reduce(
    const float* __restrict__ lossb, float* __restrict__ out)
{
  float v = lossb[threadIdx.x];
#pragma unroll
  for (int d = 32; d; d >>= 1) v += __shfl_xor(v, d);
  if (threadIdx.x == 0) out[0] = v * (1.f / 64.f);
}

// ---------------------------------------------------------------------------
extern "C" void kernel_launch(void* const* d_in, const int* in_sizes, int n_in,
                              void* d_out, int out_size, void* d_ws, size_t ws_size,
                              hipStream_t stream)
{
  const float* features = (const float*)d_in[0];
  const int*   labels   = (const int*)d_in[1];
  const float* ne_table = (const float*)d_in[2];
  const float* g1_wih_f = (const float*)d_in[3];
  const float* g1_whh_f = (const float*)d_in[4];
  const float* g1_bih_f = (const float*)d_in[5];
  const float* g1_bhh_f = (const float*)d_in[6];
  const float* g1_wih_b = (const float*)d_in[7];
  const float* g1_whh_b = (const float*)d_in[8];
  const float* g1_bih_b = (const float*)d_in[9];
  const float* g1_bhh_b = (const float*)d_in[10];
  const float* g2_wih_f = (const float*)d_in[11];
  const float* g2_whh_f = (const float*)d_in[12];
  const float* g2_bih_f = (const float*)d_in[13];
  const float* g2_bhh_f = (const float*)d_in[14];
  const float* g2_wih_b = (const float*)d_in[15];
  const float* g2_whh_b = (const float*)d_in[16];
  const float* g2_bih_b = (const float*)d_in[17];
  const float* g2_bhh_b = (const float*)d_in[18];
  const float* q_w   = (const float*)d_in[19];
  const float* q_b   = (const float*)d_in[20];
  const float* k_w   = (const float*)d_in[21];
  const float* k_b   = (const float*)d_in[22];
  const float* v_w   = (const float*)d_in[23];
  const float* v_b   = (const float*)d_in[24];
  const float* out_w = (const float*)d_in[25];
  const float* out_b = (const float*)d_in[26];
  const float* lin_w = (const float*)d_in[27];
  const float* lin_b = (const float*)d_in[28];
  const float* crf_start = (const float*)d_in[29];
  const float* crf_end   = (const float*)d_in[30];
  const float* crf_trans = (const float*)d_in[31];

  // ---- workspace layout (~218 MB) ----
  const size_t NTB = (size_t)T_SEQ * BATCH;      // 16384
  char* base = (char*)d_ws;
  size_t off = 0;
  auto alloc = [&](size_t bytes) {
    char* p = base + off;
    off += (bytes + 255) & ~(size_t)255;
    return p;
  };
  bf16* xpA  = (bf16*)alloc(NTB * G3 * sizeof(bf16));   // xp fwd (gru1, then gru2)
  bf16* xpB  = (bf16*)alloc(NTB * G3 * sizeof(bf16));   // xp bwd
  bf16* enc  = (bf16*)alloc(NTB * EMB * sizeof(bf16));  // gru1 output
  bf16* bufD = (bf16*)alloc(NTB * EMB * sizeof(bf16));  // xT -> aoraw -> dec
  bf16* bufE = (bf16*)alloc(NTB * EMB * sizeof(bf16));  // q -> aofin
  float* kkbuf  = (float*)alloc((size_t)NTAG * EMB * sizeof(float));
  float* vvbuf  = (float*)alloc((size_t)NTAG * EMB * sizeof(float));
  float* logits = (float*)alloc(NTB * NTAG * sizeof(float));
  float* lossb  = (float*)alloc(64 * sizeof(float));
  int*   bcnt   = (int*)alloc(1024 * sizeof(int));      // barrier counters
  // bf16 weight copies (~24.2 MB)
  bf16* w1if = (bf16*)alloc((size_t)G3 * FEATD * sizeof(bf16));
  bf16* w1ib = (bf16*)alloc((size_t)G3 * FEATD * sizeof(bf16));
  bf16* w1hf = (bf16*)alloc((size_t)G3 * HID * sizeof(bf16));
  bf16* w1hb = (bf16*)alloc((size_t)G3 * HID * sizeof(bf16));
  bf16* w2if = (bf16*)alloc((size_t)G3 * 2 * EMB * sizeof(bf16));
  bf16* w2ib = (bf16*)alloc((size_t)G3 * 2 * EMB * sizeof(bf16));
  bf16* w2hf = (bf16*)alloc((size_t)G3 * HID * sizeof(bf16));
  bf16* w2hb = (bf16*)alloc((size_t)G3 * HID * sizeof(bf16));
  bf16* wq   = (bf16*)alloc((size_t)EMB * EMB * sizeof(bf16));
  bf16* wo   = (bf16*)alloc((size_t)EMB * EMB * sizeof(bf16));
  (void)off; (void)ws_size; (void)in_sizes; (void)n_in; (void)out_size;

  bf16* xT = bufD;  // [T,B,FEAT] bf16, aliases bufD (dead before aoraw)

  const int M = (int)NTB;  // 16384
  dim3 blk(256);

  // 0. zero barrier counters (each launch -> replay-deterministic)
  hipMemsetAsync(bcnt, 0, 1024 * sizeof(int), stream);

  // 0b. weight conversions fp32 -> bf16
  auto conv = [&](const float* s, bf16* d, size_t n) {
    f32_to_bf16<<<(int)((n / 4 + 255) / 256), blk, 0, stream>>>(s, d, (int)(n / 4));
  };
  conv(g1_wih_f, w1if, (size_t)G3 * FEATD);
  conv(g1_wih_b, w1ib, (size_t)G3 * FEATD);
  conv(g1_whh_f, w1hf, (size_t)G3 * HID);
  conv(g1_whh_b, w1hb, (size_t)G3 * HID);
  conv(g2_wih_f, w2if, (size_t)G3 * 2 * EMB);
  conv(g2_wih_b, w2ib, (size_t)G3 * 2 * EMB);
  conv(g2_whh_f, w2hf, (size_t)G3 * HID);
  conv(g2_whh_b, w2hb, (size_t)G3 * HID);
  conv(q_w, wq, (size_t)EMB * EMB);
  conv(out_w, wo, (size_t)EMB * EMB);

  // 1. features -> [T,B,FEAT] bf16
  transpose_feat<<<(BATCH * T_SEQ * FEATD + 255) / 256, blk, 0, stream>>>(features, xT);

  dim3 g_xp(G3 / 128, M / 128);   // (12,128)
  dim3 g_e(EMB / 128, M / 128);   // (8,128)

  // 2. GRU1 input projections
  gemm_mfma<<<g_xp, blk, 0, stream>>>(xT, FEATD, nullptr, 0, FEATD,
                                      w1if, FEATD, g1_bih_f, xpA, G3, M, G3, FEATD);
  gemm_mfma<<<g_xp, blk, 0, stream>>>(xT, FEATD, nullptr, 0, FEATD,
                                      w1ib, FEATD, g1_bih_b, xpB, G3, M, G3, FEATD);

  // 3. GRU1 recurrence -> enc (single persistent launch)
  gru_persist<<<GRU_NBLK, blk, 0, stream>>>(xpA, xpB, w1hf, w1hb,
                                            g1_bhh_f, g1_bhh_b, enc, bcnt);

  // 4. K/V (batch-independent) + Q projection -> bufE
  kv_kernel<<<4, blk, 0, stream>>>(ne_table, k_w, k_b, v_w, v_b, kkbuf, vvbuf);
  gemm_mfma<<<g_e, blk, 0, stream>>>(enc, EMB, nullptr, 0, EMB,
                                     wq, EMB, q_b, bufE, EMB, M, EMB, EMB);

  // 5. Attention (q=bufE -> aoraw=bufD) + output projection (-> aofin=bufE)
  attn_kernel<<<M * 2, blk, 0, stream>>>(bufE, kkbuf, vvbuf, bufD);
  gemm_mfma<<<g_e, blk, 0, stream>>>(bufD, EMB, nullptr, 0, EMB,
                                     wo, EMB, out_b, bufE, EMB, M, EMB, EMB);

  // 6. GRU2 input projections: dec_in = [enc, ao] via concat-A GEMM
  gemm_mfma<<<g_xp, blk, 0, stream>>>(enc, EMB, bufE, EMB, EMB,
                                      w2if, 2 * EMB, g2_bih_f, xpA, G3, M, G3, 2 * EMB);
  gemm_mfma<<<g_xp, blk, 0, stream>>>(enc, EMB, bufE, EMB, EMB,
                                      w2ib, 2 * EMB, g2_bih_b, xpB, G3, M, G3, 2 * EMB);

  // 7. GRU2 recurrence -> dec (bufD; aoraw dead)
  gru_persist<<<GRU_NBLK, blk, 0, stream>>>(xpA, xpB, w2hf, w2hb,
                                            g2_bhh_f, g2_bhh_b, bufD, bcnt + 512);

  // 8. Final linear + ne logits
  dec_logits_kernel<<<M / 4, blk, 0, stream>>>(bufD, lin_w, lin_b, ne_table, logits);

  // 9. CRF NLL + mean
  crf_kernel<<<BATCH, 64, 0, stream>>>(logits, labels, crf_start, crf_end, crf_trans, lossb);
  final_reduce<<<1, 64, 0, stream>>>(lossb, (float*)d_out);
}